// Round 6
// baseline (1237.943 us; speedup 1.0000x reference)
//
#include <hip/hip_runtime.h>
#include <math.h>

#define Bb 4
#define Ll 1024
#define CSd 384
#define CPd 128
#define Hh 8
#define BL 4096
#define CAT2W 276
#define CATW 1408
#define QKVW 2208          // 512 q + 512 k + 512 v + 192 qp + 192 kp + 288 vp
#define PARTW 168          // per-row partial: o64 | og36(pad40->[64,100)) | op64 | m,l

#define S_QK 0.07216878364870322f     // 1/sqrt(3*64)
#define SQ13 0.5773502691896258f      // sqrt(1/3)
#define HW_SCALE 0.09622504486493764f // sqrt(1/108)

// ---------------------------------------------------------------------------
// gemm128: C[M,N]=A[M,K]@W[K,N](+bias). 128x128 tile, 256 thr, 8x8/thread.
// ---------------------------------------------------------------------------
template<bool RELU, bool HASBIAS>
__global__ __launch_bounds__(256) void gemm128(
    const float* __restrict__ A, int lda,
    const float* __restrict__ W, const float* __restrict__ bias,
    float* __restrict__ C, int ldc, int N, int Kd)
{
    __shared__ float As[16][128];
    __shared__ float Ws[16][128];
    const int tid = threadIdx.x;
    const int bm = blockIdx.y * 128, bn = blockIdx.x * 128;
    const int tx = tid & 15, ty = tid >> 4;
    float acc[8][8] = {};

    for (int k0 = 0; k0 < Kd; k0 += 16) {
        {
            const int m = tid >> 1, kl = (tid & 1) * 8;
            const float* ap = A + (size_t)(bm + m) * lda + k0 + kl;
            if (k0 + 16 <= Kd) {
                const float4 a0 = *(const float4*)ap;
                const float4 a1 = *(const float4*)(ap + 4);
                As[kl+0][m]=a0.x; As[kl+1][m]=a0.y; As[kl+2][m]=a0.z; As[kl+3][m]=a0.w;
                As[kl+4][m]=a1.x; As[kl+5][m]=a1.y; As[kl+6][m]=a1.z; As[kl+7][m]=a1.w;
            } else {
#pragma unroll
                for (int u = 0; u < 8; ++u)
                    As[kl+u][m] = (k0 + kl + u < Kd) ? ap[u] : 0.f;
            }
        }
        {
            const int kl = tid >> 4, n = (tid & 15) * 8;
            const bool kok = (k0 + kl) < Kd;
            const float* wp = W + (size_t)(k0 + kl) * N + bn + n;
            float4 w0 = make_float4(0,0,0,0), w1 = make_float4(0,0,0,0);
            if (kok && bn + n + 4 <= N)  w0 = *(const float4*)wp;
            if (kok && bn + n + 8 <= N)  w1 = *(const float4*)(wp + 4);
            *(float4*)&Ws[kl][n]     = w0;
            *(float4*)&Ws[kl][n + 4] = w1;
        }
        __syncthreads();
#pragma unroll
        for (int kk = 0; kk < 16; ++kk) {
            const float4 a0 = *(const float4*)&As[kk][ty*8];
            const float4 a1 = *(const float4*)&As[kk][ty*8+4];
            const float4 b0 = *(const float4*)&Ws[kk][tx*8];
            const float4 b1 = *(const float4*)&Ws[kk][tx*8+4];
            const float av[8] = {a0.x,a0.y,a0.z,a0.w,a1.x,a1.y,a1.z,a1.w};
            const float bv[8] = {b0.x,b0.y,b0.z,b0.w,b1.x,b1.y,b1.z,b1.w};
#pragma unroll
            for (int i = 0; i < 8; ++i)
#pragma unroll
                for (int j = 0; j < 8; ++j)
                    acc[i][j] = fmaf(av[i], bv[j], acc[i][j]);
        }
        __syncthreads();
    }
#pragma unroll
    for (int i = 0; i < 8; ++i) {
        const int m = bm + ty * 8 + i;
        float* cp = C + (size_t)m * ldc + bn + tx * 8;
#pragma unroll
        for (int j4 = 0; j4 < 2; ++j4) {
            const int n = bn + tx * 8 + j4 * 4;
            if (n + 4 <= N) {
                float vv[4];
#pragma unroll
                for (int u = 0; u < 4; ++u) {
                    float x = acc[i][j4*4+u];
                    if (HASBIAS) x += bias[n + u];
                    if (RELU) x = fmaxf(x, 0.f);
                    vv[u] = x;
                }
                *(float4*)(cp + j4*4) = make_float4(vv[0],vv[1],vv[2],vv[3]);
            }
        }
    }
}

// ---------------------------------------------------------------------------
// gemm64: 64x64 tile, 64 threads (1 wave), 8x8/thread, reg-prefetch dbuf.
// ---------------------------------------------------------------------------
template<bool RELU, bool HASBIAS>
__global__ __launch_bounds__(64) void gemm64(
    const float* __restrict__ A, int lda,
    const float* __restrict__ W, const float* __restrict__ bias,
    float* __restrict__ C, int ldc, int N, int Kd)
{
    __shared__ float As[16][64];
    __shared__ float Ws[16][64];
    const int tid = threadIdx.x;
    const int bm = blockIdx.y * 64, bn = blockIdx.x * 64;
    const int tx = tid & 7, ty = tid >> 3;
    const int ar = tid >> 2, ak = (tid & 3) * 4;
    const int wk = tid >> 2, wn = (tid & 3) * 16;
    float4 pa[4], pw[4];

    auto loadT = [&](int k0) {
#pragma unroll
        for (int r = 0; r < 4; ++r) {
            const int m = r * 16 + ar;
            const float* ap = A + (size_t)(bm + m) * lda + k0 + ak;
            if (k0 + 16 <= Kd) pa[r] = *(const float4*)ap;
            else {
                float t4[4];
#pragma unroll
                for (int u = 0; u < 4; ++u) t4[u] = (k0 + ak + u < Kd) ? ap[u] : 0.f;
                pa[r] = make_float4(t4[0],t4[1],t4[2],t4[3]);
            }
        }
        const bool kok = (k0 + wk) < Kd;
        const float* wp = W + (size_t)(k0 + wk) * N + bn + wn;
#pragma unroll
        for (int u = 0; u < 4; ++u)
            pw[u] = kok ? *(const float4*)(wp + u * 4) : make_float4(0,0,0,0);
    };
    auto storeT = [&]() {
#pragma unroll
        for (int r = 0; r < 4; ++r) {
            const int m = r * 16 + ar;
            As[ak+0][m] = pa[r].x; As[ak+1][m] = pa[r].y;
            As[ak+2][m] = pa[r].z; As[ak+3][m] = pa[r].w;
        }
#pragma unroll
        for (int u = 0; u < 4; ++u)
            *(float4*)&Ws[wk][wn + u * 4] = pw[u];
    };

    float acc[8][8] = {};
    loadT(0);
    for (int k0 = 0; k0 < Kd; k0 += 16) {
        storeT();
        __syncthreads();
        if (k0 + 16 < Kd) loadT(k0 + 16);
#pragma unroll
        for (int kk = 0; kk < 16; ++kk) {
            const float4 a0 = *(const float4*)&As[kk][ty*8];
            const float4 a1 = *(const float4*)&As[kk][ty*8+4];
            const float4 b0 = *(const float4*)&Ws[kk][tx*8];
            const float4 b1 = *(const float4*)&Ws[kk][tx*8+4];
            const float av[8] = {a0.x,a0.y,a0.z,a0.w,a1.x,a1.y,a1.z,a1.w};
            const float bv[8] = {b0.x,b0.y,b0.z,b0.w,b1.x,b1.y,b1.z,b1.w};
#pragma unroll
            for (int i = 0; i < 8; ++i)
#pragma unroll
                for (int j = 0; j < 8; ++j)
                    acc[i][j] = fmaf(av[i], bv[j], acc[i][j]);
        }
        __syncthreads();
    }
#pragma unroll
    for (int i = 0; i < 8; ++i) {
        const int m = bm + ty * 8 + i;
        float* cp = C + (size_t)m * ldc + bn + tx * 8;
        float vv[8];
#pragma unroll
        for (int u = 0; u < 8; ++u) {
            float x = acc[i][u];
            if (HASBIAS) x += bias[bn + tx * 8 + u];
            if (RELU) x = fmaxf(x, 0.f);
            vv[u] = x;
        }
        *(float4*)cp       = make_float4(vv[0],vv[1],vv[2],vv[3]);
        *(float4*)(cp + 4) = make_float4(vv[4],vv[5],vv[6],vv[7]);
    }
}

// ---------------------------------------------------------------------------
// weight packing
// ---------------------------------------------------------------------------
__global__ __launch_bounds__(256) void pack_qkv(
    const float* __restrict__ Wq, const float* __restrict__ Wk,
    const float* __restrict__ Wv, const float* __restrict__ Wqp,
    const float* __restrict__ Wkp, const float* __restrict__ Wvp,
    float* __restrict__ Wp)
{
    const int k = blockIdx.x;
    float* dst = Wp + (size_t)k * QKVW;
    for (int n = threadIdx.x; n < QKVW; n += 256) {
        float v;
        if      (n < 512)  v = Wq [(size_t)k*512 + n];
        else if (n < 1024) v = Wk [(size_t)k*512 + n - 512];
        else if (n < 1536) v = Wv [(size_t)k*512 + n - 1024];
        else if (n < 1728) v = Wqp[(size_t)k*192 + n - 1536];
        else if (n < 1920) v = Wkp[(size_t)k*192 + n - 1728];
        else               v = Wvp[(size_t)k*288 + n - 1920];
        dst[n] = v;
    }
}

__global__ __launch_bounds__(256) void pack_f12(
    const float* __restrict__ Wf1, const float* __restrict__ Wf2,
    const float* __restrict__ bf1, const float* __restrict__ bf2,
    float* __restrict__ Wp, float* __restrict__ bp)
{
    const int k = blockIdx.x;
    float* dst = Wp + (size_t)k * 512;
    for (int n = threadIdx.x; n < 512; n += 256)
        dst[n] = (n < 256) ? Wf1[(size_t)k*256 + n] : Wf2[(size_t)k*256 + n - 256];
    if (k == 0)
        for (int n = threadIdx.x; n < 512; n += 256)
            bp[n] = (n < 256) ? bf1[n] : bf2[n - 256];
}

// ---------------------------------------------------------------------------
// edge features: cat2[:,128:256]=pos-emb, [256:276]=neighbor distances
// ---------------------------------------------------------------------------
__global__ __launch_bounds__(128) void edge_feat(
    const float* __restrict__ trans, float* __restrict__ cat2)
{
    const int row = blockIdx.x;
    const int l = row & (Ll - 1);
    const int b = row >> 10;
    const int tid = threadIdx.x;
    {
        float v;
        if (tid < 64) {
            const float fr = __expf(-9.210340371976184f / 64.f * (float)tid);
            v = sinf((float)l * fr);
        } else {
            const float fr = __expf(-9.210340371976184f / 64.f * (float)(tid - 64));
            v = cosf((float)l * fr);
        }
        cat2[(size_t)row * CAT2W + 128 + tid] = v;
    }
    if (tid < 20) {
        const int off = (tid < 10) ? (tid - 10) : (tid - 9);
        int j = l + off;
        j = j < 0 ? 0 : (j > Ll - 1 ? Ll - 1 : j);
        const float dx = trans[(size_t)(b*Ll + j)*3 + 0] - trans[(size_t)row*3 + 0];
        const float dy = trans[(size_t)(b*Ll + j)*3 + 1] - trans[(size_t)row*3 + 1];
        const float dz = trans[(size_t)(b*Ll + j)*3 + 2] - trans[(size_t)row*3 + 2];
        cat2[(size_t)row * CAT2W + 256 + tid] = sqrtf(dx*dx + dy*dy + dz*dz);
    }
}

// ---------------------------------------------------------------------------
// z-derived factors from packed z12 [BL][512]
// ---------------------------------------------------------------------------
__global__ __launch_bounds__(256) void z_derive(
    const float* __restrict__ z12, const float* __restrict__ mask,
    const float* __restrict__ Wb1, const float* __restrict__ Wb2,
    const float* __restrict__ Wz1, const float* __restrict__ Wz2,
    float* __restrict__ bfi, float* __restrict__ bfj,
    float* __restrict__ zv1, float* __restrict__ zv2)
{
    __shared__ float zsh[512];
    const int row = blockIdx.x;
    const int tid = threadIdx.x;
    for (int idx = tid; idx < 512; idx += 256)
        zsh[idx] = z12[(size_t)row * 512 + idx];
    __syncthreads();
    const float mv = mask[row];
    if (tid < 16) {
        const int r = tid >> 3, h = tid & 7;
        float acc = 0.f;
        for (int c = 0; c < 128; ++c) acc = fmaf(zsh[r*128 + c], Wb1[c*8 + h], acc);
        bfi[(size_t)row*16 + r*8 + h] = mv * acc;
    } else if (tid < 80) {
        const int o = tid - 16, r = o >> 5, dd = o & 31;
        float acc = 0.f;
        for (int c = 0; c < 128; ++c) acc = fmaf(zsh[r*128 + c], Wz1[c*32 + dd], acc);
        zv1[(size_t)row*64 + r*32 + dd] = mv * acc;
    } else if (tid < 96) {
        const int o = tid - 80, r = o >> 3, h = o & 7;
        float acc = 0.f;
        for (int c = 0; c < 128; ++c) acc = fmaf(zsh[256 + r*128 + c], Wb2[c*8 + h], acc);
        bfj[(size_t)row*16 + r*8 + h] = mv * acc;
    } else if (tid < 160) {
        const int o = tid - 96, r = o >> 5, dd = o & 31;
        float acc = 0.f;
        for (int c = 0; c < 128; ++c) acc = fmaf(zsh[256 + r*128 + c], Wz2[c*32 + dd], acc);
        zv2[(size_t)row*64 + r*32 + dd] = mv * acc;
    }
}

// ---------------------------------------------------------------------------
// to_global on packed qkv (qp@1536, kp@1728, vp@1920), q2/k2 [B,H,L]
// ---------------------------------------------------------------------------
__global__ __launch_bounds__(256) void to_global_k(
    const float* __restrict__ rots, const float* __restrict__ trans,
    float* __restrict__ qkv, float* __restrict__ q2, float* __restrict__ k2)
{
    const int row = blockIdx.x;
    const int b = row >> 10, l = row & (Ll - 1);
    const int tid = threadIdx.x;
    __shared__ float sq[64], sk[64];
    float R[9], tn[3];
#pragma unroll
    for (int i = 0; i < 9; ++i) R[i] = rots[(size_t)row*9 + i];
#pragma unroll
    for (int i = 0; i < 3; ++i) tn[i] = trans[(size_t)row*3 + i] * 0.1f;

    float* base = nullptr;
    float* sq2 = nullptr;
    if (tid < 64)       { base = qkv + (size_t)row*QKVW + 1536 + tid*3;        sq2 = &sq[tid]; }
    else if (tid < 128) { base = qkv + (size_t)row*QKVW + 1728 + (tid-64)*3;   sq2 = &sk[tid-64]; }
    else if (tid < 224) { base = qkv + (size_t)row*QKVW + 1920 + (tid-128)*3; }
    if (base) {
        const float px = base[0], py = base[1], pz = base[2];
        const float gx = fmaf(R[0],px, fmaf(R[1],py, fmaf(R[2],pz, tn[0])));
        const float gy = fmaf(R[3],px, fmaf(R[4],py, fmaf(R[5],pz, tn[1])));
        const float gz = fmaf(R[6],px, fmaf(R[7],py, fmaf(R[8],pz, tn[2])));
        base[0] = gx; base[1] = gy; base[2] = gz;
        if (sq2) *sq2 = gx*gx + gy*gy + gz*gz;
    }
    __syncthreads();
    if (tid < 8) {
        float s2 = 0.f;
#pragma unroll
        for (int p = 0; p < 8; ++p) s2 += sq[tid*8 + p];
        q2[((size_t)b*Hh + tid)*Ll + l] = s2;
    } else if (tid < 16) {
        const int h = tid - 8;
        float s2 = 0.f;
#pragma unroll
        for (int p = 0; p < 8; ++p) s2 += sk[h*8 + p];
        k2[((size_t)b*Hh + h)*Ll + l] = s2;
    }
}

// ---------------------------------------------------------------------------
// flash IPA v3: j-split x2. Block = (bh, it, jh). 256 thr = 32 groups x 8
// lanes; each group owns rows i0=it*64+g and i0+32; processes j in
// [jh*512, jh*512+512). Writes per-row partials (o|og|op|m,l) to part.
// LDS 33.8KB -> 4 blocks/CU; grid 1024 -> 16 waves/CU.
// ---------------------------------------------------------------------------
__global__ __launch_bounds__(256) void flash_ipa3(
    const float* __restrict__ qkv,
    const float* __restrict__ q2g, const float* __restrict__ k2g,
    const float* __restrict__ bfi, const float* __restrict__ bfj,
    const float* __restrict__ zv2,
    const float* __restrict__ maskg, const float* __restrict__ gamma,
    float* __restrict__ part)
{
    __shared__ float sk[32][64];
    __shared__ float skp[32][32];
    __shared__ float sv[32][64];
    __shared__ float svp[32][36];
    __shared__ float szv[32][64];
    __shared__ float4 sjs[32];

    const int tid = threadIdx.x;
    const int t = tid & 7, g = tid >> 3;
    const int jh = blockIdx.x & 1;
    const int it = (blockIdx.x >> 1) & 15;
    const int bh = blockIdx.x >> 5;
    const int b = bh >> 3, h = bh & 7;
    const int i0 = it * 64 + g;
    const int row0 = b * Ll + i0, row1 = row0 + 32;

    const float hw = log1pf(__expf(gamma[h])) * HW_SCALE;
    const float nh = -0.5f * hw;

    float q0a[8], q1a[8], qp0[4], qp1[4];
    {
        const float* p0 = qkv + (size_t)row0 * QKVW + h * 64 + 8 * t;
        const float* p1 = qkv + (size_t)row1 * QKVW + h * 64 + 8 * t;
        const float4 a0 = *(const float4*)p0, a1 = *(const float4*)(p0 + 4);
        const float4 c0 = *(const float4*)p1, c1 = *(const float4*)(p1 + 4);
        const float t0[8] = {a0.x,a0.y,a0.z,a0.w,a1.x,a1.y,a1.z,a1.w};
        const float t1[8] = {c0.x,c0.y,c0.z,c0.w,c1.x,c1.y,c1.z,c1.w};
#pragma unroll
        for (int u = 0; u < 8; ++u) { q0a[u] = t0[u]*S_QK; q1a[u] = t1[u]*S_QK; }
        float4 e0 = make_float4(0,0,0,0), e1 = make_float4(0,0,0,0);
        if (t < 6) {
            e0 = *(const float4*)(qkv + (size_t)row0*QKVW + 1536 + h*24 + 4*t);
            e1 = *(const float4*)(qkv + (size_t)row1*QKVW + 1536 + h*24 + 4*t);
        }
        qp0[0]=e0.x*hw; qp0[1]=e0.y*hw; qp0[2]=e0.z*hw; qp0[3]=e0.w*hw;
        qp1[0]=e1.x*hw; qp1[1]=e1.y*hw; qp1[2]=e1.z*hw; qp1[3]=e1.w*hw;
    }
    const float cI0 = nh * q2g[((size_t)b*Hh + h)*Ll + i0];
    const float cI1 = nh * q2g[((size_t)b*Hh + h)*Ll + i0 + 32];
    const float bfa0 = SQ13 * bfi[(size_t)row0*16 + h];
    const float bfb0 = SQ13 * bfi[(size_t)row0*16 + 8 + h];
    const float bfa1 = SQ13 * bfi[(size_t)row1*16 + h];
    const float bfb1 = SQ13 * bfi[(size_t)row1*16 + 8 + h];

    float o0[8]={}, o1[8]={}, og0[5]={}, og1[5]={}, op0[8]={}, op1[8]={};
    float m0 = -1e30f, m1 = -1e30f, l0 = 0.f, l1 = 0.f;

    for (int jt = jh * 16; jt < jh * 16 + 16; ++jt) {
        const int rowj = b * Ll + jt * 32;
        __syncthreads();
#pragma unroll
        for (int r = 0; r < 2; ++r) {   // sk, sv, szv
            const int idx = tid + 256 * r;
            const int jj = idx >> 4, c4 = idx & 15;
            const float* src = qkv + (size_t)(rowj + jj) * QKVW;
            *(float4*)&sk[jj][c4*4]  = *(const float4*)(src + 512  + h*64 + c4*4);
            *(float4*)&sv[jj][c4*4]  = *(const float4*)(src + 1024 + h*64 + c4*4);
            *(float4*)&szv[jj][c4*4] = *(const float4*)(zv2 + (size_t)(rowj + jj)*64 + c4*4);
        }
        {   // skp (cols 24..31 zero)
            const int jj = tid >> 3, c4 = tid & 7;
            float4 v4 = make_float4(0,0,0,0);
            if (c4 < 6)
                v4 = *(const float4*)(qkv + (size_t)(rowj + jj)*QKVW + 1728 + h*24 + c4*4);
            *(float4*)&skp[jj][c4*4] = v4;
        }
#pragma unroll
        for (int r = 0; r < 2; ++r) {   // svp
            const int idx = tid + 256 * r;
            if (idx < 288) {
                const int jj = idx / 9, c4 = idx % 9;
                *(float4*)&svp[jj][c4*4] =
                    *(const float4*)(qkv + (size_t)(rowj + jj)*QKVW + 1920 + h*36 + c4*4);
            }
        }
        if (tid < 32) {
            const int j = jt * 32 + tid;
            sjs[tid] = make_float4(
                k2g[((size_t)b*Hh + h)*Ll + j],
                (maskg[(size_t)b*Ll + j] - 1.f) * 1e9f,
                bfj[(size_t)(b*Ll + j)*16 + h],
                bfj[(size_t)(b*Ll + j)*16 + 8 + h]);
        }
        __syncthreads();

        for (int jj = 0; jj < 32; ++jj) {
            const float4 ka = *(const float4*)&sk[jj][8*t];
            const float4 kb = *(const float4*)&sk[jj][8*t + 4];
            const float4 kp4 = *(const float4*)&skp[jj][4*t];
            const float kv[8] = {ka.x,ka.y,ka.z,ka.w,kb.x,kb.y,kb.z,kb.w};
            const float kpv[4] = {kp4.x,kp4.y,kp4.z,kp4.w};
            float d0 = 0.f, d1 = 0.f;
#pragma unroll
            for (int u = 0; u < 8; ++u) {
                d0 = fmaf(q0a[u], kv[u], d0);
                d1 = fmaf(q1a[u], kv[u], d1);
            }
#pragma unroll
            for (int u = 0; u < 4; ++u) {
                d0 = fmaf(qp0[u], kpv[u], d0);
                d1 = fmaf(qp1[u], kpv[u], d1);
            }
            d0 += __shfl_xor(d0, 1, 64); d0 += __shfl_xor(d0, 2, 64); d0 += __shfl_xor(d0, 4, 64);
            d1 += __shfl_xor(d1, 1, 64); d1 += __shfl_xor(d1, 2, 64); d1 += __shfl_xor(d1, 4, 64);
            const float4 js = sjs[jj];
            const float lg0 = d0 + fmaf(bfa0, js.z, fmaf(bfb0, js.w, fmaf(nh, js.x, js.y + cI0)));
            const float lg1 = d1 + fmaf(bfa1, js.z, fmaf(bfb1, js.w, fmaf(nh, js.x, js.y + cI1)));
            if (lg0 > m0) {
                const float f = __expf(m0 - lg0); m0 = lg0; l0 *= f;
#pragma unroll
                for (int u = 0; u < 8; ++u) o0[u] *= f;
#pragma unroll
                for (int u = 0; u < 5; ++u) og0[u] *= f;
#pragma unroll
                for (int u = 0; u < 8; ++u) op0[u] *= f;
            }
            const float p0 = __expf(lg0 - m0); l0 += p0;
            if (lg1 > m1) {
                const float f = __expf(m1 - lg1); m1 = lg1; l1 *= f;
#pragma unroll
                for (int u = 0; u < 8; ++u) o1[u] *= f;
#pragma unroll
                for (int u = 0; u < 5; ++u) og1[u] *= f;
#pragma unroll
                for (int u = 0; u < 8; ++u) op1[u] *= f;
            }
            const float p1 = __expf(lg1 - m1); l1 += p1;

            const float4 va = *(const float4*)&sv[jj][8*t];
            const float4 vb = *(const float4*)&sv[jj][8*t + 4];
            const float vv[8] = {va.x,va.y,va.z,va.w,vb.x,vb.y,vb.z,vb.w};
            const float4 vpa = *(const float4*)&svp[jj][4*t];
            const float vpv[4] = {vpa.x,vpa.y,vpa.z,vpa.w};
            const float vpe = svp[jj][32 + (t & 3)];
            const float vpes = (t < 4) ? vpe : 0.f;
            const float4 za = *(const float4*)&szv[jj][8*t];
            const float4 zb = *(const float4*)&szv[jj][8*t + 4];
            const float zz[8] = {za.x,za.y,za.z,za.w,zb.x,zb.y,zb.z,zb.w};
#pragma unroll
            for (int u = 0; u < 8; ++u) {
                o0[u] = fmaf(p0, vv[u], o0[u]);
                o1[u] = fmaf(p1, vv[u], o1[u]);
            }
#pragma unroll
            for (int u = 0; u < 4; ++u) {
                og0[u] = fmaf(p0, vpv[u], og0[u]);
                og1[u] = fmaf(p1, vpv[u], og1[u]);
            }
            og0[4] = fmaf(p0, vpes, og0[4]);
            og1[4] = fmaf(p1, vpes, og1[4]);
#pragma unroll
            for (int u = 0; u < 8; ++u) {
                op0[u] = fmaf(p0, zz[u], op0[u]);
                op1[u] = fmaf(p1, zz[u], op1[u]);
            }
        }
    }

    // write partials: [bh*2+jh][i][168] : o[0,64) og[64,100) op[100,164) m,l[164,166)
    float* pr0 = part + ((size_t)(bh * 2 + jh) * Ll + i0) * PARTW;
    float* pr1 = part + ((size_t)(bh * 2 + jh) * Ll + i0 + 32) * PARTW;
    *(float4*)&pr0[8*t]     = make_float4(o0[0], o0[1], o0[2], o0[3]);
    *(float4*)&pr0[8*t + 4] = make_float4(o0[4], o0[5], o0[6], o0[7]);
    *(float4*)&pr1[8*t]     = make_float4(o1[0], o1[1], o1[2], o1[3]);
    *(float4*)&pr1[8*t + 4] = make_float4(o1[4], o1[5], o1[6], o1[7]);
    *(float4*)&pr0[64 + 4*t] = make_float4(og0[0], og0[1], og0[2], og0[3]);
    *(float4*)&pr1[64 + 4*t] = make_float4(og1[0], og1[1], og1[2], og1[3]);
    if (t < 4) { pr0[96 + t] = og0[4]; pr1[96 + t] = og1[4]; }
    *(float4*)&pr0[100 + 8*t]     = make_float4(op0[0], op0[1], op0[2], op0[3]);
    *(float4*)&pr0[100 + 8*t + 4] = make_float4(op0[4], op0[5], op0[6], op0[7]);
    *(float4*)&pr1[100 + 8*t]     = make_float4(op1[0], op1[1], op1[2], op1[3]);
    *(float4*)&pr1[100 + 8*t + 4] = make_float4(op1[4], op1[5], op1[6], op1[7]);
    if (t == 0) { pr0[164] = m0; pr0[165] = l0; pr1[164] = m1; pr1[165] = l1; }
}

// ---------------------------------------------------------------------------
// combine: merge the two j-halves, normalize, apply zv1, rotate og back,
// write all of cat. Block = (bh, it): 64 rows, same group mapping as flash.
// ---------------------------------------------------------------------------
__global__ __launch_bounds__(256) void combine_ipa(
    const float* __restrict__ part,
    const float* __restrict__ zv1,
    const float* __restrict__ rots, const float* __restrict__ trans,
    float* __restrict__ cat)
{
    __shared__ float sog[64][36];
    const int tid = threadIdx.x;
    const int t = tid & 7, g = tid >> 3;
    const int it = blockIdx.x & 15;
    const int bh = blockIdx.x >> 4;
    const int b = bh >> 3, h = bh & 7;
    const int i0 = it * 64 + g;

#pragma unroll
    for (int rr = 0; rr < 2; ++rr) {
        const int i = i0 + rr * 32;
        const int row = b * Ll + i;
        const float* pA = part + ((size_t)(bh * 2 + 0) * Ll + i) * PARTW;
        const float* pB = part + ((size_t)(bh * 2 + 1) * Ll + i) * PARTW;
        const float mA = pA[164], mB = pB[164];
        const float m = fmaxf(mA, mB);
        const float wA = __expf(mA - m), wB = __expf(mB - m);
        const float l = fmaf(wA, pA[165], wB * pB[165]);
        const float sA = wA / l, sB = wB / l;

        float* crow = cat + (size_t)row * CATW;
        {   // o
            const float4 a0 = *(const float4*)&pA[8*t];
            const float4 a1 = *(const float4*)&pA[8*t + 4];
            const float4 b0 = *(const float4*)&pB[8*t];
            const float4 b1 = *(const float4*)&pB[8*t + 4];
            *(float4*)&crow[h*64 + 8*t] = make_float4(
                fmaf(sA, a0.x, sB * b0.x), fmaf(sA, a0.y, sB * b0.y),
                fmaf(sA, a0.z, sB * b0.z), fmaf(sA, a0.w, sB * b0.w));
            *(float4*)&crow[h*64 + 8*t + 4] = make_float4(
                fmaf(sA, a1.x, sB * b1.x), fmaf(sA, a1.y, sB * b1.y),
                fmaf(sA, a1.z, sB * b1.z), fmaf(sA, a1.w, sB * b1.w));
        }
        {   // opair = zv1 * blended op
            const float4 a0 = *(const float4*)&pA[100 + 8*t];
            const float4 a1 = *(const float4*)&pA[100 + 8*t + 4];
            const float4 b0 = *(const float4*)&pB[100 + 8*t];
            const float4 b1 = *(const float4*)&pB[100 + 8*t + 4];
            const float4 z0 = *(const float4*)&zv1[(size_t)row*64 + 8*t];
            const float4 z1 = *(const float4*)&zv1[(size_t)row*64 + 8*t + 4];
            *(float4*)&crow[896 + h*64 + 8*t] = make_float4(
                z0.x * fmaf(sA, a0.x, sB * b0.x), z0.y * fmaf(sA, a0.y, sB * b0.y),
                z0.z * fmaf(sA, a0.z, sB * b0.z), z0.w * fmaf(sA, a0.w, sB * b0.w));
            *(float4*)&crow[896 + h*64 + 8*t + 4] = make_float4(
                z1.x * fmaf(sA, a1.x, sB * b1.x), z1.y * fmaf(sA, a1.y, sB * b1.y),
                z1.z * fmaf(sA, a1.z, sB * b1.z), z1.w * fmaf(sA, a1.w, sB * b1.w));
        }
        {   // og -> sog
            const float4 a0 = *(const float4*)&pA[64 + 4*t];
            const float4 b0 = *(const float4*)&pB[64 + 4*t];
            sog[g + rr*32][4*t + 0] = fmaf(sA, a0.x, sB * b0.x);
            sog[g + rr*32][4*t + 1] = fmaf(sA, a0.y, sB * b0.y);
            sog[g + rr*32][4*t + 2] = fmaf(sA, a0.z, sB * b0.z);
            sog[g + rr*32][4*t + 3] = fmaf(sA, a0.w, sB * b0.w);
            if (t < 4)
                sog[g + rr*32][32 + t] = fmaf(sA, pA[96 + t], sB * pB[96 + t]);
        }
    }
    __syncthreads();
    for (int idx = tid; idx < 64 * 12; idx += 256) {
        const int ri = idx / 12, p = idx % 12;
        const int rowi = b * Ll + it * 64 + ri;
        const float ox = sog[ri][p*3 + 0] - trans[(size_t)rowi*3 + 0] * 0.1f;
        const float oy = sog[ri][p*3 + 1] - trans[(size_t)rowi*3 + 1] * 0.1f;
        const float oz = sog[ri][p*3 + 2] - trans[(size_t)rowi*3 + 2] * 0.1f;
        const float* R = rots + (size_t)rowi * 9;
        const float opx = fmaf(R[0], ox, fmaf(R[3], oy, R[6] * oz));
        const float opy = fmaf(R[1], ox, fmaf(R[4], oy, R[7] * oz));
        const float opz = fmaf(R[2], ox, fmaf(R[5], oy, R[8] * oz));
        const size_t base = (size_t)rowi * CATW + 512 + h*36 + p*3;
        cat[base + 0] = opx; cat[base + 1] = opy; cat[base + 2] = opz;
        cat[(size_t)rowi * CATW + 800 + h*12 + p] =
            sqrtf(opx*opx + opy*opy + opz*opz + 1e-8f);
    }
}

// ---------------------------------------------------------------------------
__global__ __launch_bounds__(384) void add_ln(
    const float* __restrict__ x, const float* __restrict__ y,
    const float* __restrict__ gw, const float* __restrict__ bw,
    float* __restrict__ out)
{
    __shared__ float red[6];
    const int row = blockIdx.x;
    const int c = threadIdx.x;
    const float v = x[(size_t)row*CSd + c] + y[(size_t)row*CSd + c];
    float s = v;
#pragma unroll
    for (int off = 32; off; off >>= 1) s += __shfl_down(s, off, 64);
    if ((c & 63) == 0) red[c >> 6] = s;
    __syncthreads();
    float mean = 0.f;
#pragma unroll
    for (int w = 0; w < 6; ++w) mean += red[w];
    mean *= (1.f / CSd);
    __syncthreads();
    const float d = v - mean;
    float sq = d * d;
#pragma unroll
    for (int off = 32; off; off >>= 1) sq += __shfl_down(sq, off, 64);
    if ((c & 63) == 0) red[c >> 6] = sq;
    __syncthreads();
    float var = 0.f;
#pragma unroll
    for (int w = 0; w < 6; ++w) var += red[w];
    var *= (1.f / CSd);
    out[(size_t)row*CSd + c] = d * rsqrtf(var + 1e-5f) * gw[c] + bw[c];
}

__global__ __launch_bounds__(64) void backbone(
    const float* __restrict__ s2, const float* __restrict__ Wbb,
    const float* __restrict__ bbb, const float* __restrict__ rots,
    const float* __restrict__ trans,
    float* __restrict__ outR, float* __restrict__ outT)
{
    const int row = blockIdx.x;
    const int t = threadIdx.x;
    float part[6] = {};
    for (int c = t; c < CSd; c += 64) {
        const float sv = s2[(size_t)row*CSd + c];
#pragma unroll
        for (int j = 0; j < 6; ++j) part[j] = fmaf(sv, Wbb[c*6 + j], part[j]);
    }
#pragma unroll
    for (int j = 0; j < 6; ++j) {
#pragma unroll
        for (int off = 32; off; off >>= 1) part[j] += __shfl_down(part[j], off, 64);
    }
    if (t == 0) {
        float u[6];
#pragma unroll
        for (int j = 0; j < 6; ++j) u[j] = part[j] + bbb[j];
        const float inv = 1.f / sqrtf(1.f + u[0]*u[0] + u[1]*u[1] + u[2]*u[2]);
        const float w = inv, x = u[0]*inv, y = u[1]*inv, z = u[2]*inv;
        const float Ru[9] = {
            1.f - 2.f*(y*y + z*z), 2.f*(x*y - w*z), 2.f*(x*z + w*y),
            2.f*(x*y + w*z), 1.f - 2.f*(x*x + z*z), 2.f*(y*z - w*x),
            2.f*(x*z - w*y), 2.f*(y*z + w*x), 1.f - 2.f*(x*x + y*y)};
        float R[9];
#pragma unroll
        for (int i2 = 0; i2 < 9; ++i2) R[i2] = rots[(size_t)row*9 + i2];
#pragma unroll
        for (int xi = 0; xi < 3; ++xi)
#pragma unroll
            for (int zi = 0; zi < 3; ++zi)
                outR[(size_t)row*9 + xi*3 + zi] =
                    fmaf(R[xi*3+0], Ru[0+zi],
                    fmaf(R[xi*3+1], Ru[3+zi], R[xi*3+2] * Ru[6+zi]));
#pragma unroll
        for (int xi = 0; xi < 3; ++xi)
            outT[(size_t)row*3 + xi] =
                fmaf(R[xi*3+0], u[3],
                fmaf(R[xi*3+1], u[4], R[xi*3+2] * u[5])) +
                trans[(size_t)row*3 + xi];
    }
}

// ---------------------------------------------------------------------------
extern "C" void kernel_launch(void* const* d_in, const int* in_sizes, int n_in,
                              void* d_out, int out_size, void* d_ws, size_t ws_size,
                              hipStream_t stream)
{
    const float* s      = (const float*)d_in[0];
    const float* trans  = (const float*)d_in[1];
    const float* rots   = (const float*)d_in[2];
    const float* mask   = (const float*)d_in[3];
    const float* We_s   = (const float*)d_in[4];
    const float* be_s   = (const float*)d_in[5];
    const float* We_mlp = (const float*)d_in[6];
    const float* be_mlp = (const float*)d_in[7];
    const float* Wf1    = (const float*)d_in[8];
    const float* bf1    = (const float*)d_in[9];
    const float* Wf2    = (const float*)d_in[10];
    const float* bf2    = (const float*)d_in[11];
    const float* Wq     = (const float*)d_in[12];
    const float* Wk     = (const float*)d_in[13];
    const float* Wv     = (const float*)d_in[14];
    const float* Wqp    = (const float*)d_in[15];
    const float* Wkp    = (const float*)d_in[16];
    const float* Wvp    = (const float*)d_in[17];
    const float* gamma  = (const float*)d_in[18];
    const float* Wb1    = (const float*)d_in[19];
    const float* Wb2    = (const float*)d_in[20];
    const float* Wz1    = (const float*)d_in[21];
    const float* Wz2    = (const float*)d_in[22];
    const float* Wout   = (const float*)d_in[23];
    const float* bout   = (const float*)d_in[24];
    const float* ln1_g  = (const float*)d_in[25];
    const float* ln1_b  = (const float*)d_in[26];
    const float* Wt1    = (const float*)d_in[27];
    const float* bt1    = (const float*)d_in[28];
    const float* Wt2    = (const float*)d_in[29];
    const float* bt2    = (const float*)d_in[30];
    const float* Wt3    = (const float*)d_in[31];
    const float* bt3    = (const float*)d_in[32];
    const float* ln2_g  = (const float*)d_in[33];
    const float* ln2_b  = (const float*)d_in[34];
    const float* Wbb    = (const float*)d_in[35];
    const float* bbb    = (const float*)d_in[36];

    float* ws = (float*)d_ws;
    size_t off = 0;
    auto alloc = [&](size_t n) { float* p = ws + off; off += n; return p; };
    float* cat2  = alloc((size_t)BL * CAT2W);
    float* hmid  = alloc((size_t)BL * 128);
    float* z12   = alloc((size_t)BL * 512);
    float* bfi   = alloc((size_t)BL * 16);
    float* bfj   = alloc((size_t)BL * 16);
    float* zv1   = alloc((size_t)BL * 64);
    float* zv2   = alloc((size_t)BL * 64);
    float* qkv   = alloc((size_t)BL * QKVW);
    float* q2    = alloc((size_t)BL * 8);
    float* k2    = alloc((size_t)BL * 8);
    float* cat   = alloc((size_t)BL * CATW);
    float* tmp1  = alloc((size_t)BL * CSd);
    float* s1    = alloc((size_t)BL * CSd);
    float* Wpk   = alloc((size_t)CSd * QKVW);
    float* Wf12  = alloc((size_t)128 * 512);
    float* bf12  = alloc(512);
    float* partb = alloc((size_t)32 * 2 * Ll * PARTW);   // 44 MB j-split partials
    // aliases (lifetimes: z12 dead after z_derive; qkv dead after flash)
    float* h1    = z12;
    float* h2b   = qkv;
    float* tmp2  = tmp1;

    float* outS = (float*)d_out;
    float* outR = outS + (size_t)BL * CSd;
    float* outT = outR + (size_t)BL * 9;

    pack_qkv<<<dim3(CSd), dim3(256), 0, stream>>>(Wq, Wk, Wv, Wqp, Wkp, Wvp, Wpk);
    pack_f12<<<dim3(128), dim3(256), 0, stream>>>(Wf1, Wf2, bf1, bf2, Wf12, bf12);

    // edge embedder
    gemm64<false,true><<<dim3(2,64), dim3(64), 0, stream>>>(s, CSd, We_s, be_s, cat2, CAT2W, 128, CSd);
    edge_feat<<<dim3(BL), dim3(128), 0, stream>>>(trans, cat2);
    gemm64<true,true><<<dim3(2,64), dim3(64), 0, stream>>>(cat2, CAT2W, We_mlp, be_mlp, hmid, 128, 128, CAT2W);
    gemm64<false,true><<<dim3(8,64), dim3(64), 0, stream>>>(hmid, 128, Wf12, bf12, z12, 512, 512, 128);
    z_derive<<<dim3(BL), dim3(256), 0, stream>>>(z12, mask, Wb1, Wb2, Wz1, Wz2, bfi, bfj, zv1, zv2);

    // fused QKV + point projections
    gemm128<false,false><<<dim3(18,32), dim3(256), 0, stream>>>(s, CSd, Wpk, nullptr, qkv, QKVW, QKVW, CSd);
    to_global_k<<<dim3(BL), dim3(256), 0, stream>>>(rots, trans, qkv, q2, k2);

    // fused IPA attention (j-split x2) -> partials -> combine -> cat
    flash_ipa3<<<dim3(1024), dim3(256), 0, stream>>>(
        qkv, q2, k2, bfi, bfj, zv2, mask, gamma, partb);
    combine_ipa<<<dim3(512), dim3(256), 0, stream>>>(partb, zv1, rots, trans, cat);

    // output projection + residual + LN1
    gemm64<false,true><<<dim3(6,64), dim3(64), 0, stream>>>(cat, CATW, Wout, bout, tmp1, CSd, CSd, CATW);
    add_ln<<<dim3(BL), dim3(384), 0, stream>>>(s, tmp1, ln1_g, ln1_b, s1);

    // transition
    gemm64<true,true><<<dim3(6,64), dim3(64), 0, stream>>>(s1, CSd, Wt1, bt1, h1, CSd, CSd, CSd);
    gemm64<true,true><<<dim3(6,64), dim3(64), 0, stream>>>(h1, CSd, Wt2, bt2, h2b, CSd, CSd, CSd);
    gemm64<false,true><<<dim3(6,64), dim3(64), 0, stream>>>(h2b, CSd, Wt3, bt3, tmp2, CSd, CSd, CSd);
    add_ln<<<dim3(BL), dim3(384), 0, stream>>>(s1, tmp2, ln2_g, ln2_b, outS);

    // backbone update
    backbone<<<dim3(BL), dim3(64), 0, stream>>>(outS, Wbb, bbb, rots, trans, outR, outT);
}

// Round 7
// 1104.503 us; speedup vs baseline: 1.1208x; 1.1208x over previous
//
#include <hip/hip_runtime.h>
#include <math.h>

#define Bb 4
#define Ll 1024
#define CSd 384
#define CPd 128
#define Hh 8
#define BL 4096
#define CAT2W 276
#define CATW 1408
#define QKVW 2208          // 512 q + 512 k + 512 v + 192 qp + 192 kp + 288 vp
#define PARTW 168          // per-row partial: o64 | og36(pad->[64,100)) | op64 | m,l

#define S_QK 0.07216878364870322f     // 1/sqrt(3*64)
#define SQ13 0.5773502691896258f      // sqrt(1/3)
#define HW_SCALE 0.09622504486493764f // sqrt(1/108)

// ---------------------------------------------------------------------------
// gemm128: C[M,N]=A[M,K]@W[K,N](+bias). 128x128 tile, 256 thr, 8x8/thread.
// ---------------------------------------------------------------------------
template<bool RELU, bool HASBIAS>
__global__ __launch_bounds__(256) void gemm128(
    const float* __restrict__ A, int lda,
    const float* __restrict__ W, const float* __restrict__ bias,
    float* __restrict__ C, int ldc, int N, int Kd)
{
    __shared__ float As[16][128];
    __shared__ float Ws[16][128];
    const int tid = threadIdx.x;
    const int bm = blockIdx.y * 128, bn = blockIdx.x * 128;
    const int tx = tid & 15, ty = tid >> 4;
    float acc[8][8] = {};

    for (int k0 = 0; k0 < Kd; k0 += 16) {
        {
            const int m = tid >> 1, kl = (tid & 1) * 8;
            const float* ap = A + (size_t)(bm + m) * lda + k0 + kl;
            if (k0 + 16 <= Kd) {
                const float4 a0 = *(const float4*)ap;
                const float4 a1 = *(const float4*)(ap + 4);
                As[kl+0][m]=a0.x; As[kl+1][m]=a0.y; As[kl+2][m]=a0.z; As[kl+3][m]=a0.w;
                As[kl+4][m]=a1.x; As[kl+5][m]=a1.y; As[kl+6][m]=a1.z; As[kl+7][m]=a1.w;
            } else {
#pragma unroll
                for (int u = 0; u < 8; ++u)
                    As[kl+u][m] = (k0 + kl + u < Kd) ? ap[u] : 0.f;
            }
        }
        {
            const int kl = tid >> 4, n = (tid & 15) * 8;
            const bool kok = (k0 + kl) < Kd;
            const float* wp = W + (size_t)(k0 + kl) * N + bn + n;
            float4 w0 = make_float4(0,0,0,0), w1 = make_float4(0,0,0,0);
            if (kok && bn + n + 4 <= N)  w0 = *(const float4*)wp;
            if (kok && bn + n + 8 <= N)  w1 = *(const float4*)(wp + 4);
            *(float4*)&Ws[kl][n]     = w0;
            *(float4*)&Ws[kl][n + 4] = w1;
        }
        __syncthreads();
#pragma unroll
        for (int kk = 0; kk < 16; ++kk) {
            const float4 a0 = *(const float4*)&As[kk][ty*8];
            const float4 a1 = *(const float4*)&As[kk][ty*8+4];
            const float4 b0 = *(const float4*)&Ws[kk][tx*8];
            const float4 b1 = *(const float4*)&Ws[kk][tx*8+4];
            const float av[8] = {a0.x,a0.y,a0.z,a0.w,a1.x,a1.y,a1.z,a1.w};
            const float bv[8] = {b0.x,b0.y,b0.z,b0.w,b1.x,b1.y,b1.z,b1.w};
#pragma unroll
            for (int i = 0; i < 8; ++i)
#pragma unroll
                for (int j = 0; j < 8; ++j)
                    acc[i][j] = fmaf(av[i], bv[j], acc[i][j]);
        }
        __syncthreads();
    }
#pragma unroll
    for (int i = 0; i < 8; ++i) {
        const int m = bm + ty * 8 + i;
        float* cp = C + (size_t)m * ldc + bn + tx * 8;
#pragma unroll
        for (int j4 = 0; j4 < 2; ++j4) {
            const int n = bn + tx * 8 + j4 * 4;
            if (n + 4 <= N) {
                float vv[4];
#pragma unroll
                for (int u = 0; u < 4; ++u) {
                    float x = acc[i][j4*4+u];
                    if (HASBIAS) x += bias[n + u];
                    if (RELU) x = fmaxf(x, 0.f);
                    vv[u] = x;
                }
                *(float4*)(cp + j4*4) = make_float4(vv[0],vv[1],vv[2],vv[3]);
            }
        }
    }
}

// ---------------------------------------------------------------------------
// gemm64: 64x64 tile, 64 threads (1 wave), 8x8/thread, reg-prefetch dbuf.
// ---------------------------------------------------------------------------
template<bool RELU, bool HASBIAS>
__global__ __launch_bounds__(64) void gemm64(
    const float* __restrict__ A, int lda,
    const float* __restrict__ W, const float* __restrict__ bias,
    float* __restrict__ C, int ldc, int N, int Kd)
{
    __shared__ float As[16][64];
    __shared__ float Ws[16][64];
    const int tid = threadIdx.x;
    const int bm = blockIdx.y * 64, bn = blockIdx.x * 64;
    const int tx = tid & 7, ty = tid >> 3;
    const int ar = tid >> 2, ak = (tid & 3) * 4;
    const int wk = tid >> 2, wn = (tid & 3) * 16;
    float4 pa[4], pw[4];

    auto loadT = [&](int k0) {
#pragma unroll
        for (int r = 0; r < 4; ++r) {
            const int m = r * 16 + ar;
            const float* ap = A + (size_t)(bm + m) * lda + k0 + ak;
            if (k0 + 16 <= Kd) pa[r] = *(const float4*)ap;
            else {
                float t4[4];
#pragma unroll
                for (int u = 0; u < 4; ++u) t4[u] = (k0 + ak + u < Kd) ? ap[u] : 0.f;
                pa[r] = make_float4(t4[0],t4[1],t4[2],t4[3]);
            }
        }
        const bool kok = (k0 + wk) < Kd;
        const float* wp = W + (size_t)(k0 + wk) * N + bn + wn;
#pragma unroll
        for (int u = 0; u < 4; ++u)
            pw[u] = kok ? *(const float4*)(wp + u * 4) : make_float4(0,0,0,0);
    };
    auto storeT = [&]() {
#pragma unroll
        for (int r = 0; r < 4; ++r) {
            const int m = r * 16 + ar;
            As[ak+0][m] = pa[r].x; As[ak+1][m] = pa[r].y;
            As[ak+2][m] = pa[r].z; As[ak+3][m] = pa[r].w;
        }
#pragma unroll
        for (int u = 0; u < 4; ++u)
            *(float4*)&Ws[wk][wn + u * 4] = pw[u];
    };

    float acc[8][8] = {};
    loadT(0);
    for (int k0 = 0; k0 < Kd; k0 += 16) {
        storeT();
        __syncthreads();
        if (k0 + 16 < Kd) loadT(k0 + 16);
#pragma unroll
        for (int kk = 0; kk < 16; ++kk) {
            const float4 a0 = *(const float4*)&As[kk][ty*8];
            const float4 a1 = *(const float4*)&As[kk][ty*8+4];
            const float4 b0 = *(const float4*)&Ws[kk][tx*8];
            const float4 b1 = *(const float4*)&Ws[kk][tx*8+4];
            const float av[8] = {a0.x,a0.y,a0.z,a0.w,a1.x,a1.y,a1.z,a1.w};
            const float bv[8] = {b0.x,b0.y,b0.z,b0.w,b1.x,b1.y,b1.z,b1.w};
#pragma unroll
            for (int i = 0; i < 8; ++i)
#pragma unroll
                for (int j = 0; j < 8; ++j)
                    acc[i][j] = fmaf(av[i], bv[j], acc[i][j]);
        }
        __syncthreads();
    }
#pragma unroll
    for (int i = 0; i < 8; ++i) {
        const int m = bm + ty * 8 + i;
        float* cp = C + (size_t)m * ldc + bn + tx * 8;
        float vv[8];
#pragma unroll
        for (int u = 0; u < 8; ++u) {
            float x = acc[i][u];
            if (HASBIAS) x += bias[bn + tx * 8 + u];
            if (RELU) x = fmaxf(x, 0.f);
            vv[u] = x;
        }
        *(float4*)cp       = make_float4(vv[0],vv[1],vv[2],vv[3]);
        *(float4*)(cp + 4) = make_float4(vv[4],vv[5],vv[6],vv[7]);
    }
}

// ---------------------------------------------------------------------------
// weight packing
// ---------------------------------------------------------------------------
__global__ __launch_bounds__(256) void pack_qkv(
    const float* __restrict__ Wq, const float* __restrict__ Wk,
    const float* __restrict__ Wv, const float* __restrict__ Wqp,
    const float* __restrict__ Wkp, const float* __restrict__ Wvp,
    float* __restrict__ Wp)
{
    const int k = blockIdx.x;
    float* dst = Wp + (size_t)k * QKVW;
    for (int n = threadIdx.x; n < QKVW; n += 256) {
        float v;
        if      (n < 512)  v = Wq [(size_t)k*512 + n];
        else if (n < 1024) v = Wk [(size_t)k*512 + n - 512];
        else if (n < 1536) v = Wv [(size_t)k*512 + n - 1024];
        else if (n < 1728) v = Wqp[(size_t)k*192 + n - 1536];
        else if (n < 1920) v = Wkp[(size_t)k*192 + n - 1728];
        else               v = Wvp[(size_t)k*288 + n - 1920];
        dst[n] = v;
    }
}

__global__ __launch_bounds__(256) void pack_f12(
    const float* __restrict__ Wf1, const float* __restrict__ Wf2,
    const float* __restrict__ bf1, const float* __restrict__ bf2,
    float* __restrict__ Wp, float* __restrict__ bp)
{
    const int k = blockIdx.x;
    float* dst = Wp + (size_t)k * 512;
    for (int n = threadIdx.x; n < 512; n += 256)
        dst[n] = (n < 256) ? Wf1[(size_t)k*256 + n] : Wf2[(size_t)k*256 + n - 256];
    if (k == 0)
        for (int n = threadIdx.x; n < 512; n += 256)
            bp[n] = (n < 256) ? bf1[n] : bf2[n - 256];
}

// ---------------------------------------------------------------------------
// edge features: cat2[:,128:256]=pos-emb, [256:276]=neighbor distances
// ---------------------------------------------------------------------------
__global__ __launch_bounds__(128) void edge_feat(
    const float* __restrict__ trans, float* __restrict__ cat2)
{
    const int row = blockIdx.x;
    const int l = row & (Ll - 1);
    const int b = row >> 10;
    const int tid = threadIdx.x;
    {
        float v;
        if (tid < 64) {
            const float fr = __expf(-9.210340371976184f / 64.f * (float)tid);
            v = sinf((float)l * fr);
        } else {
            const float fr = __expf(-9.210340371976184f / 64.f * (float)(tid - 64));
            v = cosf((float)l * fr);
        }
        cat2[(size_t)row * CAT2W + 128 + tid] = v;
    }
    if (tid < 20) {
        const int off = (tid < 10) ? (tid - 10) : (tid - 9);
        int j = l + off;
        j = j < 0 ? 0 : (j > Ll - 1 ? Ll - 1 : j);
        const float dx = trans[(size_t)(b*Ll + j)*3 + 0] - trans[(size_t)row*3 + 0];
        const float dy = trans[(size_t)(b*Ll + j)*3 + 1] - trans[(size_t)row*3 + 1];
        const float dz = trans[(size_t)(b*Ll + j)*3 + 2] - trans[(size_t)row*3 + 2];
        cat2[(size_t)row * CAT2W + 256 + tid] = sqrtf(dx*dx + dy*dy + dz*dz);
    }
}

// ---------------------------------------------------------------------------
// z-derived factors from packed z12 [BL][512]
// ---------------------------------------------------------------------------
__global__ __launch_bounds__(256) void z_derive(
    const float* __restrict__ z12, const float* __restrict__ mask,
    const float* __restrict__ Wb1, const float* __restrict__ Wb2,
    const float* __restrict__ Wz1, const float* __restrict__ Wz2,
    float* __restrict__ bfi, float* __restrict__ bfj,
    float* __restrict__ zv1, float* __restrict__ zv2)
{
    __shared__ float zsh[512];
    const int row = blockIdx.x;
    const int tid = threadIdx.x;
    for (int idx = tid; idx < 512; idx += 256)
        zsh[idx] = z12[(size_t)row * 512 + idx];
    __syncthreads();
    const float mv = mask[row];
    if (tid < 16) {
        const int r = tid >> 3, h = tid & 7;
        float acc = 0.f;
        for (int c = 0; c < 128; ++c) acc = fmaf(zsh[r*128 + c], Wb1[c*8 + h], acc);
        bfi[(size_t)row*16 + r*8 + h] = mv * acc;
    } else if (tid < 80) {
        const int o = tid - 16, r = o >> 5, dd = o & 31;
        float acc = 0.f;
        for (int c = 0; c < 128; ++c) acc = fmaf(zsh[r*128 + c], Wz1[c*32 + dd], acc);
        zv1[(size_t)row*64 + r*32 + dd] = mv * acc;
    } else if (tid < 96) {
        const int o = tid - 80, r = o >> 3, h = o & 7;
        float acc = 0.f;
        for (int c = 0; c < 128; ++c) acc = fmaf(zsh[256 + r*128 + c], Wb2[c*8 + h], acc);
        bfj[(size_t)row*16 + r*8 + h] = mv * acc;
    } else if (tid < 160) {
        const int o = tid - 96, r = o >> 5, dd = o & 31;
        float acc = 0.f;
        for (int c = 0; c < 128; ++c) acc = fmaf(zsh[256 + r*128 + c], Wz2[c*32 + dd], acc);
        zv2[(size_t)row*64 + r*32 + dd] = mv * acc;
    }
}

// ---------------------------------------------------------------------------
// to_global on packed qkv (qp@1536, kp@1728, vp@1920), q2/k2 [B,H,L]
// ---------------------------------------------------------------------------
__global__ __launch_bounds__(256) void to_global_k(
    const float* __restrict__ rots, const float* __restrict__ trans,
    float* __restrict__ qkv, float* __restrict__ q2, float* __restrict__ k2)
{
    const int row = blockIdx.x;
    const int b = row >> 10, l = row & (Ll - 1);
    const int tid = threadIdx.x;
    __shared__ float sq[64], sk[64];
    float R[9], tn[3];
#pragma unroll
    for (int i = 0; i < 9; ++i) R[i] = rots[(size_t)row*9 + i];
#pragma unroll
    for (int i = 0; i < 3; ++i) tn[i] = trans[(size_t)row*3 + i] * 0.1f;

    float* base = nullptr;
    float* sq2 = nullptr;
    if (tid < 64)       { base = qkv + (size_t)row*QKVW + 1536 + tid*3;        sq2 = &sq[tid]; }
    else if (tid < 128) { base = qkv + (size_t)row*QKVW + 1728 + (tid-64)*3;   sq2 = &sk[tid-64]; }
    else if (tid < 224) { base = qkv + (size_t)row*QKVW + 1920 + (tid-128)*3; }
    if (base) {
        const float px = base[0], py = base[1], pz = base[2];
        const float gx = fmaf(R[0],px, fmaf(R[1],py, fmaf(R[2],pz, tn[0])));
        const float gy = fmaf(R[3],px, fmaf(R[4],py, fmaf(R[5],pz, tn[1])));
        const float gz = fmaf(R[6],px, fmaf(R[7],py, fmaf(R[8],pz, tn[2])));
        base[0] = gx; base[1] = gy; base[2] = gz;
        if (sq2) *sq2 = gx*gx + gy*gy + gz*gz;
    }
    __syncthreads();
    if (tid < 8) {
        float s2 = 0.f;
#pragma unroll
        for (int p = 0; p < 8; ++p) s2 += sq[tid*8 + p];
        q2[((size_t)b*Hh + tid)*Ll + l] = s2;
    } else if (tid < 16) {
        const int h = tid - 8;
        float s2 = 0.f;
#pragma unroll
        for (int p = 0; p < 8; ++p) s2 += sk[h*8 + p];
        k2[((size_t)b*Hh + h)*Ll + l] = s2;
    }
}

// ---------------------------------------------------------------------------
// flash IPA v4: 4 rows per group (DS reads amortized x4). Block = (bh,it,jh);
// 256 thr = 32 groups x 8 lanes; group g owns rows it*128+g+{0,32,64,96};
// processes j in [jh*512, jh*512+512). Writes per-row partials to part.
// Grid 512 = 2 blocks/CU (measured residency limit). DS instrs/row halved
// vs v3 -> DS pipe and VALU pipe both ~saturated.
// ---------------------------------------------------------------------------
__global__ __launch_bounds__(256, 2) void flash_ipa4(
    const float* __restrict__ qkv,
    const float* __restrict__ q2g, const float* __restrict__ k2g,
    const float* __restrict__ bfi, const float* __restrict__ bfj,
    const float* __restrict__ zv2,
    const float* __restrict__ maskg, const float* __restrict__ gamma,
    float* __restrict__ part)
{
    __shared__ float sk[32][64];
    __shared__ float skp[32][32];
    __shared__ float sv[32][64];
    __shared__ float svp[32][36];
    __shared__ float szv[32][64];
    __shared__ float4 sjs[32];

    const int tid = threadIdx.x;
    const int t = tid & 7, g = tid >> 3;
    const int jh = blockIdx.x & 1;
    const int it = (blockIdx.x >> 1) & 7;
    const int bh = blockIdx.x >> 4;
    const int b = bh >> 3, h = bh & 7;
    const int i0 = it * 128 + g;

    const float hw = log1pf(__expf(gamma[h])) * HW_SCALE;
    const float nh = -0.5f * hw;

    // q-side registers for 4 rows (scales folded in)
    float qa[4][8], qp[4][4], cI[4], bfa[4], bfb[4];
#pragma unroll
    for (int rr = 0; rr < 4; ++rr) {
        const int row = b * Ll + i0 + 32 * rr;
        const float* p0 = qkv + (size_t)row * QKVW + h * 64 + 8 * t;
        const float4 a0 = *(const float4*)p0, a1 = *(const float4*)(p0 + 4);
        qa[rr][0]=a0.x*S_QK; qa[rr][1]=a0.y*S_QK; qa[rr][2]=a0.z*S_QK; qa[rr][3]=a0.w*S_QK;
        qa[rr][4]=a1.x*S_QK; qa[rr][5]=a1.y*S_QK; qa[rr][6]=a1.z*S_QK; qa[rr][7]=a1.w*S_QK;
        float4 e0 = make_float4(0,0,0,0);
        if (t < 6)
            e0 = *(const float4*)(qkv + (size_t)row*QKVW + 1536 + h*24 + 4*t);
        qp[rr][0]=e0.x*hw; qp[rr][1]=e0.y*hw; qp[rr][2]=e0.z*hw; qp[rr][3]=e0.w*hw;
        cI[rr]  = nh * q2g[((size_t)b*Hh + h)*Ll + i0 + 32*rr];
        bfa[rr] = SQ13 * bfi[(size_t)row*16 + h];
        bfb[rr] = SQ13 * bfi[(size_t)row*16 + 8 + h];
    }

    float o[4][8] = {}, og[4][5] = {}, op[4][8] = {};
    float m[4] = {-1e30f,-1e30f,-1e30f,-1e30f}, l[4] = {};

    for (int jt = jh * 16; jt < jh * 16 + 16; ++jt) {
        const int rowj = b * Ll + jt * 32;
        __syncthreads();
#pragma unroll
        for (int r = 0; r < 2; ++r) {   // sk, sv, szv
            const int idx = tid + 256 * r;
            const int jj = idx >> 4, c4 = idx & 15;
            const float* src = qkv + (size_t)(rowj + jj) * QKVW;
            *(float4*)&sk[jj][c4*4]  = *(const float4*)(src + 512  + h*64 + c4*4);
            *(float4*)&sv[jj][c4*4]  = *(const float4*)(src + 1024 + h*64 + c4*4);
            *(float4*)&szv[jj][c4*4] = *(const float4*)(zv2 + (size_t)(rowj + jj)*64 + c4*4);
        }
        {   // skp (cols 24..31 zero)
            const int jj = tid >> 3, c4 = tid & 7;
            float4 v4 = make_float4(0,0,0,0);
            if (c4 < 6)
                v4 = *(const float4*)(qkv + (size_t)(rowj + jj)*QKVW + 1728 + h*24 + c4*4);
            *(float4*)&skp[jj][c4*4] = v4;
        }
#pragma unroll
        for (int r = 0; r < 2; ++r) {   // svp
            const int idx = tid + 256 * r;
            if (idx < 288) {
                const int jj = idx / 9, c4 = idx % 9;
                *(float4*)&svp[jj][c4*4] =
                    *(const float4*)(qkv + (size_t)(rowj + jj)*QKVW + 1920 + h*36 + c4*4);
            }
        }
        if (tid < 32) {
            const int j = jt * 32 + tid;
            sjs[tid] = make_float4(
                k2g[((size_t)b*Hh + h)*Ll + j],
                (maskg[(size_t)b*Ll + j] - 1.f) * 1e9f,
                bfj[(size_t)(b*Ll + j)*16 + h],
                bfj[(size_t)(b*Ll + j)*16 + 8 + h]);
        }
        __syncthreads();

        for (int jj = 0; jj < 32; ++jj) {
            const float4 ka = *(const float4*)&sk[jj][8*t];
            const float4 kb = *(const float4*)&sk[jj][8*t + 4];
            const float4 kp4 = *(const float4*)&skp[jj][4*t];
            const float kv[8] = {ka.x,ka.y,ka.z,ka.w,kb.x,kb.y,kb.z,kb.w};
            const float kpv[4] = {kp4.x,kp4.y,kp4.z,kp4.w};
            float d[4];
#pragma unroll
            for (int rr = 0; rr < 4; ++rr) {
                float dd = 0.f;
#pragma unroll
                for (int u = 0; u < 8; ++u) dd = fmaf(qa[rr][u], kv[u], dd);
#pragma unroll
                for (int u = 0; u < 4; ++u) dd = fmaf(qp[rr][u], kpv[u], dd);
                d[rr] = dd;
            }
#pragma unroll
            for (int rr = 0; rr < 4; ++rr) {
                d[rr] += __shfl_xor(d[rr], 1, 64);
                d[rr] += __shfl_xor(d[rr], 2, 64);
                d[rr] += __shfl_xor(d[rr], 4, 64);
            }
            const float4 js = sjs[jj];

            const float4 va = *(const float4*)&sv[jj][8*t];
            const float4 vb = *(const float4*)&sv[jj][8*t + 4];
            const float vv[8] = {va.x,va.y,va.z,va.w,vb.x,vb.y,vb.z,vb.w};
            const float4 vpa = *(const float4*)&svp[jj][4*t];
            const float vpv[4] = {vpa.x,vpa.y,vpa.z,vpa.w};
            const float vpe = svp[jj][32 + (t & 3)];
            const float vpes = (t < 4) ? vpe : 0.f;
            const float4 za = *(const float4*)&szv[jj][8*t];
            const float4 zb = *(const float4*)&szv[jj][8*t + 4];
            const float zz[8] = {za.x,za.y,za.z,za.w,zb.x,zb.y,zb.z,zb.w};

#pragma unroll
            for (int rr = 0; rr < 4; ++rr) {
                const float lg = d[rr] +
                    fmaf(bfa[rr], js.z, fmaf(bfb[rr], js.w, fmaf(nh, js.x, js.y + cI[rr])));
                if (lg > m[rr]) {
                    const float f = __expf(m[rr] - lg); m[rr] = lg; l[rr] *= f;
#pragma unroll
                    for (int u = 0; u < 8; ++u) o[rr][u] *= f;
#pragma unroll
                    for (int u = 0; u < 5; ++u) og[rr][u] *= f;
#pragma unroll
                    for (int u = 0; u < 8; ++u) op[rr][u] *= f;
                }
                const float p = __expf(lg - m[rr]); l[rr] += p;
#pragma unroll
                for (int u = 0; u < 8; ++u) o[rr][u] = fmaf(p, vv[u], o[rr][u]);
#pragma unroll
                for (int u = 0; u < 4; ++u) og[rr][u] = fmaf(p, vpv[u], og[rr][u]);
                og[rr][4] = fmaf(p, vpes, og[rr][4]);
#pragma unroll
                for (int u = 0; u < 8; ++u) op[rr][u] = fmaf(p, zz[u], op[rr][u]);
            }
        }
    }

    // write partials: [bh*2+jh][i][168] : o[0,64) og[64,100) op[100,164) m,l[164,166)
#pragma unroll
    for (int rr = 0; rr < 4; ++rr) {
        float* pr = part + ((size_t)(bh * 2 + jh) * Ll + i0 + 32 * rr) * PARTW;
        *(float4*)&pr[8*t]     = make_float4(o[rr][0], o[rr][1], o[rr][2], o[rr][3]);
        *(float4*)&pr[8*t + 4] = make_float4(o[rr][4], o[rr][5], o[rr][6], o[rr][7]);
        *(float4*)&pr[64 + 4*t] = make_float4(og[rr][0], og[rr][1], og[rr][2], og[rr][3]);
        if (t < 4) pr[96 + t] = og[rr][4];
        *(float4*)&pr[100 + 8*t]     = make_float4(op[rr][0], op[rr][1], op[rr][2], op[rr][3]);
        *(float4*)&pr[100 + 8*t + 4] = make_float4(op[rr][4], op[rr][5], op[rr][6], op[rr][7]);
        if (t == 0) { pr[164] = m[rr]; pr[165] = l[rr]; }
    }
}

// ---------------------------------------------------------------------------
// combine: merge the two j-halves, normalize, apply zv1, rotate og back,
// write all of cat. Block = (bh, it): 64 rows.
// ---------------------------------------------------------------------------
__global__ __launch_bounds__(256) void combine_ipa(
    const float* __restrict__ part,
    const float* __restrict__ zv1,
    const float* __restrict__ rots, const float* __restrict__ trans,
    float* __restrict__ cat)
{
    __shared__ float sog[64][36];
    const int tid = threadIdx.x;
    const int t = tid & 7, g = tid >> 3;
    const int it = blockIdx.x & 15;
    const int bh = blockIdx.x >> 4;
    const int b = bh >> 3, h = bh & 7;
    const int i0 = it * 64 + g;

#pragma unroll
    for (int rr = 0; rr < 2; ++rr) {
        const int i = i0 + rr * 32;
        const int row = b * Ll + i;
        const float* pA = part + ((size_t)(bh * 2 + 0) * Ll + i) * PARTW;
        const float* pB = part + ((size_t)(bh * 2 + 1) * Ll + i) * PARTW;
        const float mA = pA[164], mB = pB[164];
        const float m = fmaxf(mA, mB);
        const float wA = __expf(mA - m), wB = __expf(mB - m);
        const float l = fmaf(wA, pA[165], wB * pB[165]);
        const float sA = wA / l, sB = wB / l;

        float* crow = cat + (size_t)row * CATW;
        {   // o
            const float4 a0 = *(const float4*)&pA[8*t];
            const float4 a1 = *(const float4*)&pA[8*t + 4];
            const float4 b0 = *(const float4*)&pB[8*t];
            const float4 b1 = *(const float4*)&pB[8*t + 4];
            *(float4*)&crow[h*64 + 8*t] = make_float4(
                fmaf(sA, a0.x, sB * b0.x), fmaf(sA, a0.y, sB * b0.y),
                fmaf(sA, a0.z, sB * b0.z), fmaf(sA, a0.w, sB * b0.w));
            *(float4*)&crow[h*64 + 8*t + 4] = make_float4(
                fmaf(sA, a1.x, sB * b1.x), fmaf(sA, a1.y, sB * b1.y),
                fmaf(sA, a1.z, sB * b1.z), fmaf(sA, a1.w, sB * b1.w));
        }
        {   // opair = zv1 * blended op
            const float4 a0 = *(const float4*)&pA[100 + 8*t];
            const float4 a1 = *(const float4*)&pA[100 + 8*t + 4];
            const float4 b0 = *(const float4*)&pB[100 + 8*t];
            const float4 b1 = *(const float4*)&pB[100 + 8*t + 4];
            const float4 z0 = *(const float4*)&zv1[(size_t)row*64 + 8*t];
            const float4 z1 = *(const float4*)&zv1[(size_t)row*64 + 8*t + 4];
            *(float4*)&crow[896 + h*64 + 8*t] = make_float4(
                z0.x * fmaf(sA, a0.x, sB * b0.x), z0.y * fmaf(sA, a0.y, sB * b0.y),
                z0.z * fmaf(sA, a0.z, sB * b0.z), z0.w * fmaf(sA, a0.w, sB * b0.w));
            *(float4*)&crow[896 + h*64 + 8*t + 4] = make_float4(
                z1.x * fmaf(sA, a1.x, sB * b1.x), z1.y * fmaf(sA, a1.y, sB * b1.y),
                z1.z * fmaf(sA, a1.z, sB * b1.z), z1.w * fmaf(sA, a1.w, sB * b1.w));
        }
        {   // og -> sog
            const float4 a0 = *(const float4*)&pA[64 + 4*t];
            const float4 b0 = *(const float4*)&pB[64 + 4*t];
            sog[g + rr*32][4*t + 0] = fmaf(sA, a0.x, sB * b0.x);
            sog[g + rr*32][4*t + 1] = fmaf(sA, a0.y, sB * b0.y);
            sog[g + rr*32][4*t + 2] = fmaf(sA, a0.z, sB * b0.z);
            sog[g + rr*32][4*t + 3] = fmaf(sA, a0.w, sB * b0.w);
            if (t < 4)
                sog[g + rr*32][32 + t] = fmaf(sA, pA[96 + t], sB * pB[96 + t]);
        }
    }
    __syncthreads();
    for (int idx = tid; idx < 64 * 12; idx += 256) {
        const int ri = idx / 12, p = idx % 12;
        const int rowi = b * Ll + it * 64 + ri;
        const float ox = sog[ri][p*3 + 0] - trans[(size_t)rowi*3 + 0] * 0.1f;
        const float oy = sog[ri][p*3 + 1] - trans[(size_t)rowi*3 + 1] * 0.1f;
        const float oz = sog[ri][p*3 + 2] - trans[(size_t)rowi*3 + 2] * 0.1f;
        const float* R = rots + (size_t)rowi * 9;
        const float opx = fmaf(R[0], ox, fmaf(R[3], oy, R[6] * oz));
        const float opy = fmaf(R[1], ox, fmaf(R[4], oy, R[7] * oz));
        const float opz = fmaf(R[2], ox, fmaf(R[5], oy, R[8] * oz));
        const size_t base = (size_t)rowi * CATW + 512 + h*36 + p*3;
        cat[base + 0] = opx; cat[base + 1] = opy; cat[base + 2] = opz;
        cat[(size_t)rowi * CATW + 800 + h*12 + p] =
            sqrtf(opx*opx + opy*opy + opz*opz + 1e-8f);
    }
}

// ---------------------------------------------------------------------------
__global__ __launch_bounds__(384) void add_ln(
    const float* __restrict__ x, const float* __restrict__ y,
    const float* __restrict__ gw, const float* __restrict__ bw,
    float* __restrict__ out)
{
    __shared__ float red[6];
    const int row = blockIdx.x;
    const int c = threadIdx.x;
    const float v = x[(size_t)row*CSd + c] + y[(size_t)row*CSd + c];
    float s = v;
#pragma unroll
    for (int off = 32; off; off >>= 1) s += __shfl_down(s, off, 64);
    if ((c & 63) == 0) red[c >> 6] = s;
    __syncthreads();
    float mean = 0.f;
#pragma unroll
    for (int w = 0; w < 6; ++w) mean += red[w];
    mean *= (1.f / CSd);
    __syncthreads();
    const float d = v - mean;
    float sq = d * d;
#pragma unroll
    for (int off = 32; off; off >>= 1) sq += __shfl_down(sq, off, 64);
    if ((c & 63) == 0) red[c >> 6] = sq;
    __syncthreads();
    float var = 0.f;
#pragma unroll
    for (int w = 0; w < 6; ++w) var += red[w];
    var *= (1.f / CSd);
    out[(size_t)row*CSd + c] = d * rsqrtf(var + 1e-5f) * gw[c] + bw[c];
}

__global__ __launch_bounds__(64) void backbone(
    const float* __restrict__ s2, const float* __restrict__ Wbb,
    const float* __restrict__ bbb, const float* __restrict__ rots,
    const float* __restrict__ trans,
    float* __restrict__ outR, float* __restrict__ outT)
{
    const int row = blockIdx.x;
    const int t = threadIdx.x;
    float part[6] = {};
    for (int c = t; c < CSd; c += 64) {
        const float sv = s2[(size_t)row*CSd + c];
#pragma unroll
        for (int j = 0; j < 6; ++j) part[j] = fmaf(sv, Wbb[c*6 + j], part[j]);
    }
#pragma unroll
    for (int j = 0; j < 6; ++j) {
#pragma unroll
        for (int off = 32; off; off >>= 1) part[j] += __shfl_down(part[j], off, 64);
    }
    if (t == 0) {
        float u[6];
#pragma unroll
        for (int j = 0; j < 6; ++j) u[j] = part[j] + bbb[j];
        const float inv = 1.f / sqrtf(1.f + u[0]*u[0] + u[1]*u[1] + u[2]*u[2]);
        const float w = inv, x = u[0]*inv, y = u[1]*inv, z = u[2]*inv;
        const float Ru[9] = {
            1.f - 2.f*(y*y + z*z), 2.f*(x*y - w*z), 2.f*(x*z + w*y),
            2.f*(x*y + w*z), 1.f - 2.f*(x*x + z*z), 2.f*(y*z - w*x),
            2.f*(x*z - w*y), 2.f*(y*z + w*x), 1.f - 2.f*(x*x + y*y)};
        float R[9];
#pragma unroll
        for (int i2 = 0; i2 < 9; ++i2) R[i2] = rots[(size_t)row*9 + i2];
#pragma unroll
        for (int xi = 0; xi < 3; ++xi)
#pragma unroll
            for (int zi = 0; zi < 3; ++zi)
                outR[(size_t)row*9 + xi*3 + zi] =
                    fmaf(R[xi*3+0], Ru[0+zi],
                    fmaf(R[xi*3+1], Ru[3+zi], R[xi*3+2] * Ru[6+zi]));
#pragma unroll
        for (int xi = 0; xi < 3; ++xi)
            outT[(size_t)row*3 + xi] =
                fmaf(R[xi*3+0], u[3],
                fmaf(R[xi*3+1], u[4], R[xi*3+2] * u[5])) +
                trans[(size_t)row*3 + xi];
    }
}

// ---------------------------------------------------------------------------
extern "C" void kernel_launch(void* const* d_in, const int* in_sizes, int n_in,
                              void* d_out, int out_size, void* d_ws, size_t ws_size,
                              hipStream_t stream)
{
    const float* s      = (const float*)d_in[0];
    const float* trans  = (const float*)d_in[1];
    const float* rots   = (const float*)d_in[2];
    const float* mask   = (const float*)d_in[3];
    const float* We_s   = (const float*)d_in[4];
    const float* be_s   = (const float*)d_in[5];
    const float* We_mlp = (const float*)d_in[6];
    const float* be_mlp = (const float*)d_in[7];
    const float* Wf1    = (const float*)d_in[8];
    const float* bf1    = (const float*)d_in[9];
    const float* Wf2    = (const float*)d_in[10];
    const float* bf2    = (const float*)d_in[11];
    const float* Wq     = (const float*)d_in[12];
    const float* Wk     = (const float*)d_in[13];
    const float* Wv     = (const float*)d_in[14];
    const float* Wqp    = (const float*)d_in[15];
    const float* Wkp    = (const float*)d_in[16];
    const float* Wvp    = (const float*)d_in[17];
    const float* gamma  = (const float*)d_in[18];
    const float* Wb1    = (const float*)d_in[19];
    const float* Wb2    = (const float*)d_in[20];
    const float* Wz1    = (const float*)d_in[21];
    const float* Wz2    = (const float*)d_in[22];
    const float* Wout   = (const float*)d_in[23];
    const float* bout   = (const float*)d_in[24];
    const float* ln1_g  = (const float*)d_in[25];
    const float* ln1_b  = (const float*)d_in[26];
    const float* Wt1    = (const float*)d_in[27];
    const float* bt1    = (const float*)d_in[28];
    const float* Wt2    = (const float*)d_in[29];
    const float* bt2    = (const float*)d_in[30];
    const float* Wt3    = (const float*)d_in[31];
    const float* bt3    = (const float*)d_in[32];
    const float* ln2_g  = (const float*)d_in[33];
    const float* ln2_b  = (const float*)d_in[34];
    const float* Wbb    = (const float*)d_in[35];
    const float* bbb    = (const float*)d_in[36];

    float* ws = (float*)d_ws;
    size_t off = 0;
    auto alloc = [&](size_t n) { float* p = ws + off; off += n; return p; };
    float* cat2  = alloc((size_t)BL * CAT2W);
    float* hmid  = alloc((size_t)BL * 128);
    float* z12   = alloc((size_t)BL * 512);
    float* bfi   = alloc((size_t)BL * 16);
    float* bfj   = alloc((size_t)BL * 16);
    float* zv1   = alloc((size_t)BL * 64);
    float* zv2   = alloc((size_t)BL * 64);
    float* qkv   = alloc((size_t)BL * QKVW);
    float* q2    = alloc((size_t)BL * 8);
    float* k2    = alloc((size_t)BL * 8);
    float* cat   = alloc((size_t)BL * CATW);
    float* tmp1  = alloc((size_t)BL * CSd);
    float* s1    = alloc((size_t)BL * CSd);
    float* Wpk   = alloc((size_t)CSd * QKVW);
    float* Wf12  = alloc((size_t)128 * 512);
    float* bf12  = alloc(512);
    float* partb = alloc((size_t)32 * 2 * Ll * PARTW);   // 44 MB j-split partials
    // aliases (lifetimes: z12 dead after z_derive; qkv dead after flash)
    float* h1    = z12;
    float* h2b   = qkv;
    float* tmp2  = tmp1;

    float* outS = (float*)d_out;
    float* outR = outS + (size_t)BL * CSd;
    float* outT = outR + (size_t)BL * 9;

    pack_qkv<<<dim3(CSd), dim3(256), 0, stream>>>(Wq, Wk, Wv, Wqp, Wkp, Wvp, Wpk);
    pack_f12<<<dim3(128), dim3(256), 0, stream>>>(Wf1, Wf2, bf1, bf2, Wf12, bf12);

    // edge embedder
    gemm64<false,true><<<dim3(2,64), dim3(64), 0, stream>>>(s, CSd, We_s, be_s, cat2, CAT2W, 128, CSd);
    edge_feat<<<dim3(BL), dim3(128), 0, stream>>>(trans, cat2);
    gemm64<true,true><<<dim3(2,64), dim3(64), 0, stream>>>(cat2, CAT2W, We_mlp, be_mlp, hmid, 128, 128, CAT2W);
    gemm64<false,true><<<dim3(8,64), dim3(64), 0, stream>>>(hmid, 128, Wf12, bf12, z12, 512, 512, 128);
    z_derive<<<dim3(BL), dim3(256), 0, stream>>>(z12, mask, Wb1, Wb2, Wz1, Wz2, bfi, bfj, zv1, zv2);

    // fused QKV + point projections
    gemm128<false,false><<<dim3(18,32), dim3(256), 0, stream>>>(s, CSd, Wpk, nullptr, qkv, QKVW, QKVW, CSd);
    to_global_k<<<dim3(BL), dim3(256), 0, stream>>>(rots, trans, qkv, q2, k2);

    // fused IPA attention (4 rows/group, j-split x2) -> partials -> combine
    flash_ipa4<<<dim3(512), dim3(256), 0, stream>>>(
        qkv, q2, k2, bfi, bfj, zv2, mask, gamma, partb);
    combine_ipa<<<dim3(512), dim3(256), 0, stream>>>(partb, zv1, rots, trans, cat);

    // output projection + residual + LN1
    gemm64<false,true><<<dim3(6,64), dim3(64), 0, stream>>>(cat, CATW, Wout, bout, tmp1, CSd, CSd, CATW);
    add_ln<<<dim3(BL), dim3(384), 0, stream>>>(s, tmp1, ln1_g, ln1_b, s1);

    // transition
    gemm64<true,true><<<dim3(6,64), dim3(64), 0, stream>>>(s1, CSd, Wt1, bt1, h1, CSd, CSd, CSd);
    gemm64<true,true><<<dim3(6,64), dim3(64), 0, stream>>>(h1, CSd, Wt2, bt2, h2b, CSd, CSd, CSd);
    gemm64<false,true><<<dim3(6,64), dim3(64), 0, stream>>>(h2b, CSd, Wt3, bt3, tmp2, CSd, CSd, CSd);
    add_ln<<<dim3(BL), dim3(384), 0, stream>>>(s1, tmp2, ln2_g, ln2_b, outS);

    // backbone update
    backbone<<<dim3(BL), dim3(64), 0, stream>>>(outS, Wbb, bbb, rots, trans, outR, outT);
}

// Round 8
// 807.711 us; speedup vs baseline: 1.5327x; 1.3674x over previous
//
#include <hip/hip_runtime.h>
#include <math.h>

#define Bb 4
#define Ll 1024
#define CSd 384
#define CPd 128
#define Hh 8
#define BL 4096
#define CAT2W 276
#define CATW 1408
#define QKVW 2208          // 512 q + 512 k + 512 v + 192 qp + 192 kp + 288 vp
#define PARTW 168          // per-row partial: o64 | og36(pad->[64,100)) | op64 | m,l
#define LDP 40             // LDS bf16 row pitch (80 B = 16B-aligned, 2-way banks)

#define S_QK 0.07216878364870322f     // 1/sqrt(3*64)
#define SQ13 0.5773502691896258f      // sqrt(1/3)
#define HW_SCALE 0.09622504486493764f // sqrt(1/108)

typedef short bf16x8 __attribute__((ext_vector_type(8)));
typedef float f32x4  __attribute__((ext_vector_type(4)));

__device__ __forceinline__ ushort f2bf(float f) {
    uint u = __float_as_uint(f);
    u += 0x7FFF + ((u >> 16) & 1);          // RNE
    return (ushort)(u >> 16);
}
__device__ __forceinline__ float bf2f(ushort h) {
    return __uint_as_float(((uint)h) << 16);
}

// ---------------------------------------------------------------------------
// gemm_mfma: C[M,N] = A[M,K]@W[K,N] (+bias)(+relu), fp32 I/O, bf16x3 MFMA
// internally (~fp32 accuracy). 64x64 tile, 256 thr = 4 waves (2x2 quadrants
// of 32x32). BK=32, one mfma_f32_16x16x32_bf16 triple per 16x16 frag.
// A/B frag layout: row|col = lane&15, k = 8*(lane>>4)+i (contiguous, b128).
// C/D layout (m89-verified): col = lane&15, row = 4*(lane>>4)+reg.
// W staged col-major with XOR-8 k-block swizzle on (col>>3)&3.
// M%64==0; N,K guarded.
// ---------------------------------------------------------------------------
template<bool RELU, bool HASBIAS>
__global__ __launch_bounds__(256) void gemm_mfma(
    const float* __restrict__ A, int lda,
    const float* __restrict__ W, const float* __restrict__ bias,
    float* __restrict__ C, int ldc, int N, int Kd)
{
    __shared__ short Ah[64][LDP], Al[64][LDP];
    __shared__ short Wh[64][LDP], Wl[64][LDP];
    const int tid = threadIdx.x;
    const int lane = tid & 63;
    const int wave = tid >> 6;
    const int qm = wave >> 1, qn = wave & 1;
    const int bm = blockIdx.y * 64, bn = blockIdx.x * 64;

    f32x4 acc[2][2];
#pragma unroll
    for (int i = 0; i < 2; ++i)
#pragma unroll
        for (int j = 0; j < 2; ++j) {
            acc[i][j][0] = 0.f; acc[i][j][1] = 0.f;
            acc[i][j][2] = 0.f; acc[i][j][3] = 0.f;
        }

    const int rsel = lane & 15;
    const int ksel = (lane >> 4) * 8;

    for (int k0 = 0; k0 < Kd; k0 += 32) {
        __syncthreads();
        {   // stage A: row = tid>>2 (64), kc = (tid&3)*8
            const int row = tid >> 2, kc = (tid & 3) * 8;
            const float* ap = A + (size_t)(bm + row) * lda + k0 + kc;
            float av[8];
            if (k0 + kc + 8 <= Kd) {
                const float4 a0 = *(const float4*)ap;
                const float4 a1 = *(const float4*)(ap + 4);
                av[0]=a0.x; av[1]=a0.y; av[2]=a0.z; av[3]=a0.w;
                av[4]=a1.x; av[5]=a1.y; av[6]=a1.z; av[7]=a1.w;
            } else {
#pragma unroll
                for (int u = 0; u < 8; ++u)
                    av[u] = (k0 + kc + u < Kd) ? ap[u] : 0.f;
            }
            short hv[8], lv[8];
#pragma unroll
            for (int u = 0; u < 8; ++u) {
                const ushort h = f2bf(av[u]);
                hv[u] = (short)h;
                lv[u] = (short)f2bf(av[u] - bf2f(h));
            }
            *(bf16x8*)&Ah[row][kc] = *(const bf16x8*)hv;
            *(bf16x8*)&Al[row][kc] = *(const bf16x8*)lv;
        }
        {   // stage W col-major: col = tid&63, k-chunk = (tid>>6)*8
            const int col = tid & 63, ko = (tid >> 6) * 8;
            const int swz = ((col >> 3) & 3) << 3;
            const bool cok = (bn + col) < N;
            float wv[8];
#pragma unroll
            for (int i = 0; i < 8; ++i) {
                const int k = k0 + ko + i;
                wv[i] = (cok && k < Kd) ? W[(size_t)k * N + bn + col] : 0.f;
            }
            short hv[8], lv[8];
#pragma unroll
            for (int i = 0; i < 8; ++i) {
                const ushort h = f2bf(wv[i]);
                hv[i] = (short)h;
                lv[i] = (short)f2bf(wv[i] - bf2f(h));
            }
            *(bf16x8*)&Wh[col][ko ^ swz] = *(const bf16x8*)hv;
            *(bf16x8*)&Wl[col][ko ^ swz] = *(const bf16x8*)lv;
        }
        __syncthreads();

        bf16x8 afh[2], afl[2], wfh[2], wfl[2];
#pragma unroll
        for (int fr = 0; fr < 2; ++fr) {
            const int row = qm * 32 + fr * 16 + rsel;
            afh[fr] = *(const bf16x8*)&Ah[row][ksel];
            afl[fr] = *(const bf16x8*)&Al[row][ksel];
        }
#pragma unroll
        for (int fc = 0; fc < 2; ++fc) {
            const int col = qn * 32 + fc * 16 + rsel;
            const int swz = ((col >> 3) & 3) << 3;
            wfh[fc] = *(const bf16x8*)&Wh[col][ksel ^ swz];
            wfl[fc] = *(const bf16x8*)&Wl[col][ksel ^ swz];
        }
#pragma unroll
        for (int fr = 0; fr < 2; ++fr)
#pragma unroll
            for (int fc = 0; fc < 2; ++fc) {
                acc[fr][fc] = __builtin_amdgcn_mfma_f32_16x16x32_bf16(
                    afh[fr], wfh[fc], acc[fr][fc], 0, 0, 0);
                acc[fr][fc] = __builtin_amdgcn_mfma_f32_16x16x32_bf16(
                    afh[fr], wfl[fc], acc[fr][fc], 0, 0, 0);
                acc[fr][fc] = __builtin_amdgcn_mfma_f32_16x16x32_bf16(
                    afl[fr], wfh[fc], acc[fr][fc], 0, 0, 0);
            }
    }

#pragma unroll
    for (int fr = 0; fr < 2; ++fr)
#pragma unroll
        for (int fc = 0; fc < 2; ++fc) {
            const int col = bn + qn * 32 + fc * 16 + rsel;
            if (col < N) {
                const float bv = HASBIAS ? bias[col] : 0.f;
#pragma unroll
                for (int r = 0; r < 4; ++r) {
                    const int row = bm + qm * 32 + fr * 16 + (lane >> 4) * 4 + r;
                    float x = acc[fr][fc][r] + bv;
                    if (RELU) x = fmaxf(x, 0.f);
                    C[(size_t)row * ldc + col] = x;
                }
            }
        }
}

// ---------------------------------------------------------------------------
// weight packing
// ---------------------------------------------------------------------------
__global__ __launch_bounds__(256) void pack_qkv(
    const float* __restrict__ Wq, const float* __restrict__ Wk,
    const float* __restrict__ Wv, const float* __restrict__ Wqp,
    const float* __restrict__ Wkp, const float* __restrict__ Wvp,
    float* __restrict__ Wp)
{
    const int k = blockIdx.x;
    float* dst = Wp + (size_t)k * QKVW;
    for (int n = threadIdx.x; n < QKVW; n += 256) {
        float v;
        if      (n < 512)  v = Wq [(size_t)k*512 + n];
        else if (n < 1024) v = Wk [(size_t)k*512 + n - 512];
        else if (n < 1536) v = Wv [(size_t)k*512 + n - 1024];
        else if (n < 1728) v = Wqp[(size_t)k*192 + n - 1536];
        else if (n < 1920) v = Wkp[(size_t)k*192 + n - 1728];
        else               v = Wvp[(size_t)k*288 + n - 1920];
        dst[n] = v;
    }
}

__global__ __launch_bounds__(256) void pack_f12(
    const float* __restrict__ Wf1, const float* __restrict__ Wf2,
    const float* __restrict__ bf1, const float* __restrict__ bf2,
    float* __restrict__ Wp, float* __restrict__ bp)
{
    const int k = blockIdx.x;
    float* dst = Wp + (size_t)k * 512;
    for (int n = threadIdx.x; n < 512; n += 256)
        dst[n] = (n < 256) ? Wf1[(size_t)k*256 + n] : Wf2[(size_t)k*256 + n - 256];
    if (k == 0)
        for (int n = threadIdx.x; n < 512; n += 256)
            bp[n] = (n < 256) ? bf1[n] : bf2[n - 256];
}

// ---------------------------------------------------------------------------
// edge features: cat2[:,128:256]=pos-emb, [256:276]=neighbor distances
// ---------------------------------------------------------------------------
__global__ __launch_bounds__(128) void edge_feat(
    const float* __restrict__ trans, float* __restrict__ cat2)
{
    const int row = blockIdx.x;
    const int l = row & (Ll - 1);
    const int b = row >> 10;
    const int tid = threadIdx.x;
    {
        float v;
        if (tid < 64) {
            const float fr = __expf(-9.210340371976184f / 64.f * (float)tid);
            v = sinf((float)l * fr);
        } else {
            const float fr = __expf(-9.210340371976184f / 64.f * (float)(tid - 64));
            v = cosf((float)l * fr);
        }
        cat2[(size_t)row * CAT2W + 128 + tid] = v;
    }
    if (tid < 20) {
        const int off = (tid < 10) ? (tid - 10) : (tid - 9);
        int j = l + off;
        j = j < 0 ? 0 : (j > Ll - 1 ? Ll - 1 : j);
        const float dx = trans[(size_t)(b*Ll + j)*3 + 0] - trans[(size_t)row*3 + 0];
        const float dy = trans[(size_t)(b*Ll + j)*3 + 1] - trans[(size_t)row*3 + 1];
        const float dz = trans[(size_t)(b*Ll + j)*3 + 2] - trans[(size_t)row*3 + 2];
        cat2[(size_t)row * CAT2W + 256 + tid] = sqrtf(dx*dx + dy*dy + dz*dz);
    }
}

// ---------------------------------------------------------------------------
// z-derived factors from packed z12 [BL][512]
// ---------------------------------------------------------------------------
__global__ __launch_bounds__(256) void z_derive(
    const float* __restrict__ z12, const float* __restrict__ mask,
    const float* __restrict__ Wb1, const float* __restrict__ Wb2,
    const float* __restrict__ Wz1, const float* __restrict__ Wz2,
    float* __restrict__ bfi, float* __restrict__ bfj,
    float* __restrict__ zv1, float* __restrict__ zv2)
{
    __shared__ float zsh[512];
    const int row = blockIdx.x;
    const int tid = threadIdx.x;
    for (int idx = tid; idx < 512; idx += 256)
        zsh[idx] = z12[(size_t)row * 512 + idx];
    __syncthreads();
    const float mv = mask[row];
    if (tid < 16) {
        const int r = tid >> 3, h = tid & 7;
        float acc = 0.f;
        for (int c = 0; c < 128; ++c) acc = fmaf(zsh[r*128 + c], Wb1[c*8 + h], acc);
        bfi[(size_t)row*16 + r*8 + h] = mv * acc;
    } else if (tid < 80) {
        const int o = tid - 16, r = o >> 5, dd = o & 31;
        float acc = 0.f;
        for (int c = 0; c < 128; ++c) acc = fmaf(zsh[r*128 + c], Wz1[c*32 + dd], acc);
        zv1[(size_t)row*64 + r*32 + dd] = mv * acc;
    } else if (tid < 96) {
        const int o = tid - 80, r = o >> 3, h = o & 7;
        float acc = 0.f;
        for (int c = 0; c < 128; ++c) acc = fmaf(zsh[256 + r*128 + c], Wb2[c*8 + h], acc);
        bfj[(size_t)row*16 + r*8 + h] = mv * acc;
    } else if (tid < 160) {
        const int o = tid - 96, r = o >> 5, dd = o & 31;
        float acc = 0.f;
        for (int c = 0; c < 128; ++c) acc = fmaf(zsh[256 + r*128 + c], Wz2[c*32 + dd], acc);
        zv2[(size_t)row*64 + r*32 + dd] = mv * acc;
    }
}

// ---------------------------------------------------------------------------
// to_global on packed qkv (qp@1536, kp@1728, vp@1920), q2/k2 [B,H,L]
// ---------------------------------------------------------------------------
__global__ __launch_bounds__(256) void to_global_k(
    const float* __restrict__ rots, const float* __restrict__ trans,
    float* __restrict__ qkv, float* __restrict__ q2, float* __restrict__ k2)
{
    const int row = blockIdx.x;
    const int b = row >> 10, l = row & (Ll - 1);
    const int tid = threadIdx.x;
    __shared__ float sq[64], sk[64];
    float R[9], tn[3];
#pragma unroll
    for (int i = 0; i < 9; ++i) R[i] = rots[(size_t)row*9 + i];
#pragma unroll
    for (int i = 0; i < 3; ++i) tn[i] = trans[(size_t)row*3 + i] * 0.1f;

    float* base = nullptr;
    float* sq2 = nullptr;
    if (tid < 64)       { base = qkv + (size_t)row*QKVW + 1536 + tid*3;        sq2 = &sq[tid]; }
    else if (tid < 128) { base = qkv + (size_t)row*QKVW + 1728 + (tid-64)*3;   sq2 = &sk[tid-64]; }
    else if (tid < 224) { base = qkv + (size_t)row*QKVW + 1920 + (tid-128)*3; }
    if (base) {
        const float px = base[0], py = base[1], pz = base[2];
        const float gx = fmaf(R[0],px, fmaf(R[1],py, fmaf(R[2],pz, tn[0])));
        const float gy = fmaf(R[3],px, fmaf(R[4],py, fmaf(R[5],pz, tn[1])));
        const float gz = fmaf(R[6],px, fmaf(R[7],py, fmaf(R[8],pz, tn[2])));
        base[0] = gx; base[1] = gy; base[2] = gz;
        if (sq2) *sq2 = gx*gx + gy*gy + gz*gz;
    }
    __syncthreads();
    if (tid < 8) {
        float s2 = 0.f;
#pragma unroll
        for (int p = 0; p < 8; ++p) s2 += sq[tid*8 + p];
        q2[((size_t)b*Hh + tid)*Ll + l] = s2;
    } else if (tid < 16) {
        const int h = tid - 8;
        float s2 = 0.f;
#pragma unroll
        for (int p = 0; p < 8; ++p) s2 += sk[h*8 + p];
        k2[((size_t)b*Hh + h)*Ll + l] = s2;
    }
}

// ---------------------------------------------------------------------------
// flash IPA v4: 4 rows per group, j-split x2 (unchanged from round 7).
// ---------------------------------------------------------------------------
__global__ __launch_bounds__(256, 2) void flash_ipa4(
    const float* __restrict__ qkv,
    const float* __restrict__ q2g, const float* __restrict__ k2g,
    const float* __restrict__ bfi, const float* __restrict__ bfj,
    const float* __restrict__ zv2,
    const float* __restrict__ maskg, const float* __restrict__ gamma,
    float* __restrict__ part)
{
    __shared__ float sk[32][64];
    __shared__ float skp[32][32];
    __shared__ float sv[32][64];
    __shared__ float svp[32][36];
    __shared__ float szv[32][64];
    __shared__ float4 sjs[32];

    const int tid = threadIdx.x;
    const int t = tid & 7, g = tid >> 3;
    const int jh = blockIdx.x & 1;
    const int it = (blockIdx.x >> 1) & 7;
    const int bh = blockIdx.x >> 4;
    const int b = bh >> 3, h = bh & 7;
    const int i0 = it * 128 + g;

    const float hw = log1pf(__expf(gamma[h])) * HW_SCALE;
    const float nh = -0.5f * hw;

    float qa[4][8], qp[4][4], cI[4], bfa[4], bfb[4];
#pragma unroll
    for (int rr = 0; rr < 4; ++rr) {
        const int row = b * Ll + i0 + 32 * rr;
        const float* p0 = qkv + (size_t)row * QKVW + h * 64 + 8 * t;
        const float4 a0 = *(const float4*)p0, a1 = *(const float4*)(p0 + 4);
        qa[rr][0]=a0.x*S_QK; qa[rr][1]=a0.y*S_QK; qa[rr][2]=a0.z*S_QK; qa[rr][3]=a0.w*S_QK;
        qa[rr][4]=a1.x*S_QK; qa[rr][5]=a1.y*S_QK; qa[rr][6]=a1.z*S_QK; qa[rr][7]=a1.w*S_QK;
        float4 e0 = make_float4(0,0,0,0);
        if (t < 6)
            e0 = *(const float4*)(qkv + (size_t)row*QKVW + 1536 + h*24 + 4*t);
        qp[rr][0]=e0.x*hw; qp[rr][1]=e0.y*hw; qp[rr][2]=e0.z*hw; qp[rr][3]=e0.w*hw;
        cI[rr]  = nh * q2g[((size_t)b*Hh + h)*Ll + i0 + 32*rr];
        bfa[rr] = SQ13 * bfi[(size_t)row*16 + h];
        bfb[rr] = SQ13 * bfi[(size_t)row*16 + 8 + h];
    }

    float o[4][8] = {}, og[4][5] = {}, op[4][8] = {};
    float m[4] = {-1e30f,-1e30f,-1e30f,-1e30f}, l[4] = {};

    for (int jt = jh * 16; jt < jh * 16 + 16; ++jt) {
        const int rowj = b * Ll + jt * 32;
        __syncthreads();
#pragma unroll
        for (int r = 0; r < 2; ++r) {
            const int idx = tid + 256 * r;
            const int jj = idx >> 4, c4 = idx & 15;
            const float* src = qkv + (size_t)(rowj + jj) * QKVW;
            *(float4*)&sk[jj][c4*4]  = *(const float4*)(src + 512  + h*64 + c4*4);
            *(float4*)&sv[jj][c4*4]  = *(const float4*)(src + 1024 + h*64 + c4*4);
            *(float4*)&szv[jj][c4*4] = *(const float4*)(zv2 + (size_t)(rowj + jj)*64 + c4*4);
        }
        {
            const int jj = tid >> 3, c4 = tid & 7;
            float4 v4 = make_float4(0,0,0,0);
            if (c4 < 6)
                v4 = *(const float4*)(qkv + (size_t)(rowj + jj)*QKVW + 1728 + h*24 + c4*4);
            *(float4*)&skp[jj][c4*4] = v4;
        }
#pragma unroll
        for (int r = 0; r < 2; ++r) {
            const int idx = tid + 256 * r;
            if (idx < 288) {
                const int jj = idx / 9, c4 = idx % 9;
                *(float4*)&svp[jj][c4*4] =
                    *(const float4*)(qkv + (size_t)(rowj + jj)*QKVW + 1920 + h*36 + c4*4);
            }
        }
        if (tid < 32) {
            const int j = jt * 32 + tid;
            sjs[tid] = make_float4(
                k2g[((size_t)b*Hh + h)*Ll + j],
                (maskg[(size_t)b*Ll + j] - 1.f) * 1e9f,
                bfj[(size_t)(b*Ll + j)*16 + h],
                bfj[(size_t)(b*Ll + j)*16 + 8 + h]);
        }
        __syncthreads();

        for (int jj = 0; jj < 32; ++jj) {
            const float4 ka = *(const float4*)&sk[jj][8*t];
            const float4 kb = *(const float4*)&sk[jj][8*t + 4];
            const float4 kp4 = *(const float4*)&skp[jj][4*t];
            const float kv[8] = {ka.x,ka.y,ka.z,ka.w,kb.x,kb.y,kb.z,kb.w};
            const float kpv[4] = {kp4.x,kp4.y,kp4.z,kp4.w};
            float d[4];
#pragma unroll
            for (int rr = 0; rr < 4; ++rr) {
                float dd = 0.f;
#pragma unroll
                for (int u = 0; u < 8; ++u) dd = fmaf(qa[rr][u], kv[u], dd);
#pragma unroll
                for (int u = 0; u < 4; ++u) dd = fmaf(qp[rr][u], kpv[u], dd);
                d[rr] = dd;
            }
#pragma unroll
            for (int rr = 0; rr < 4; ++rr) {
                d[rr] += __shfl_xor(d[rr], 1, 64);
                d[rr] += __shfl_xor(d[rr], 2, 64);
                d[rr] += __shfl_xor(d[rr], 4, 64);
            }
            const float4 js = sjs[jj];

            const float4 va = *(const float4*)&sv[jj][8*t];
            const float4 vb = *(const float4*)&sv[jj][8*t + 4];
            const float vv[8] = {va.x,va.y,va.z,va.w,vb.x,vb.y,vb.z,vb.w};
            const float4 vpa = *(const float4*)&svp[jj][4*t];
            const float vpv[4] = {vpa.x,vpa.y,vpa.z,vpa.w};
            const float vpe = svp[jj][32 + (t & 3)];
            const float vpes = (t < 4) ? vpe : 0.f;
            const float4 za = *(const float4*)&szv[jj][8*t];
            const float4 zb = *(const float4*)&szv[jj][8*t + 4];
            const float zz[8] = {za.x,za.y,za.z,za.w,zb.x,zb.y,zb.z,zb.w};

#pragma unroll
            for (int rr = 0; rr < 4; ++rr) {
                const float lg = d[rr] +
                    fmaf(bfa[rr], js.z, fmaf(bfb[rr], js.w, fmaf(nh, js.x, js.y + cI[rr])));
                if (lg > m[rr]) {
                    const float f = __expf(m[rr] - lg); m[rr] = lg; l[rr] *= f;
#pragma unroll
                    for (int u = 0; u < 8; ++u) o[rr][u] *= f;
#pragma unroll
                    for (int u = 0; u < 5; ++u) og[rr][u] *= f;
#pragma unroll
                    for (int u = 0; u < 8; ++u) op[rr][u] *= f;
                }
                const float p = __expf(lg - m[rr]); l[rr] += p;
#pragma unroll
                for (int u = 0; u < 8; ++u) o[rr][u] = fmaf(p, vv[u], o[rr][u]);
#pragma unroll
                for (int u = 0; u < 4; ++u) og[rr][u] = fmaf(p, vpv[u], og[rr][u]);
                og[rr][4] = fmaf(p, vpes, og[rr][4]);
#pragma unroll
                for (int u = 0; u < 8; ++u) op[rr][u] = fmaf(p, zz[u], op[rr][u]);
            }
        }
    }

#pragma unroll
    for (int rr = 0; rr < 4; ++rr) {
        float* pr = part + ((size_t)(bh * 2 + jh) * Ll + i0 + 32 * rr) * PARTW;
        *(float4*)&pr[8*t]     = make_float4(o[rr][0], o[rr][1], o[rr][2], o[rr][3]);
        *(float4*)&pr[8*t + 4] = make_float4(o[rr][4], o[rr][5], o[rr][6], o[rr][7]);
        *(float4*)&pr[64 + 4*t] = make_float4(og[rr][0], og[rr][1], og[rr][2], og[rr][3]);
        if (t < 4) pr[96 + t] = og[rr][4];
        *(float4*)&pr[100 + 8*t]     = make_float4(op[rr][0], op[rr][1], op[rr][2], op[rr][3]);
        *(float4*)&pr[100 + 8*t + 4] = make_float4(op[rr][4], op[rr][5], op[rr][6], op[rr][7]);
        if (t == 0) { pr[164] = m[rr]; pr[165] = l[rr]; }
    }
}

// ---------------------------------------------------------------------------
// combine: merge the two j-halves, normalize, apply zv1, rotate og back.
// ---------------------------------------------------------------------------
__global__ __launch_bounds__(256) void combine_ipa(
    const float* __restrict__ part,
    const float* __restrict__ zv1,
    const float* __restrict__ rots, const float* __restrict__ trans,
    float* __restrict__ cat)
{
    __shared__ float sog[64][36];
    const int tid = threadIdx.x;
    const int t = tid & 7, g = tid >> 3;
    const int it = blockIdx.x & 15;
    const int bh = blockIdx.x >> 4;
    const int b = bh >> 3, h = bh & 7;
    const int i0 = it * 64 + g;

#pragma unroll
    for (int rr = 0; rr < 2; ++rr) {
        const int i = i0 + rr * 32;
        const int row = b * Ll + i;
        const float* pA = part + ((size_t)(bh * 2 + 0) * Ll + i) * PARTW;
        const float* pB = part + ((size_t)(bh * 2 + 1) * Ll + i) * PARTW;
        const float mA = pA[164], mB = pB[164];
        const float m = fmaxf(mA, mB);
        const float wA = __expf(mA - m), wB = __expf(mB - m);
        const float l = fmaf(wA, pA[165], wB * pB[165]);
        const float sA = wA / l, sB = wB / l;

        float* crow = cat + (size_t)row * CATW;
        {
            const float4 a0 = *(const float4*)&pA[8*t];
            const float4 a1 = *(const float4*)&pA[8*t + 4];
            const float4 b0 = *(const float4*)&pB[8*t];
            const float4 b1 = *(const float4*)&pB[8*t + 4];
            *(float4*)&crow[h*64 + 8*t] = make_float4(
                fmaf(sA, a0.x, sB * b0.x), fmaf(sA, a0.y, sB * b0.y),
                fmaf(sA, a0.z, sB * b0.z), fmaf(sA, a0.w, sB * b0.w));
            *(float4*)&crow[h*64 + 8*t + 4] = make_float4(
                fmaf(sA, a1.x, sB * b1.x), fmaf(sA, a1.y, sB * b1.y),
                fmaf(sA, a1.z, sB * b1.z), fmaf(sA, a1.w, sB * b1.w));
        }
        {
            const float4 a0 = *(const float4*)&pA[100 + 8*t];
            const float4 a1 = *(const float4*)&pA[100 + 8*t + 4];
            const float4 b0 = *(const float4*)&pB[100 + 8*t];
            const float4 b1 = *(const float4*)&pB[100 + 8*t + 4];
            const float4 z0 = *(const float4*)&zv1[(size_t)row*64 + 8*t];
            const float4 z1 = *(const float4*)&zv1[(size_t)row*64 + 8*t + 4];
            *(float4*)&crow[896 + h*64 + 8*t] = make_float4(
                z0.x * fmaf(sA, a0.x, sB * b0.x), z0.y * fmaf(sA, a0.y, sB * b0.y),
                z0.z * fmaf(sA, a0.z, sB * b0.z), z0.w * fmaf(sA, a0.w, sB * b0.w));
            *(float4*)&crow[896 + h*64 + 8*t + 4] = make_float4(
                z1.x * fmaf(sA, a1.x, sB * b1.x), z1.y * fmaf(sA, a1.y, sB * b1.y),
                z1.z * fmaf(sA, a1.z, sB * b1.z), z1.w * fmaf(sA, a1.w, sB * b1.w));
        }
        {
            const float4 a0 = *(const float4*)&pA[64 + 4*t];
            const float4 b0 = *(const float4*)&pB[64 + 4*t];
            sog[g + rr*32][4*t + 0] = fmaf(sA, a0.x, sB * b0.x);
            sog[g + rr*32][4*t + 1] = fmaf(sA, a0.y, sB * b0.y);
            sog[g + rr*32][4*t + 2] = fmaf(sA, a0.z, sB * b0.z);
            sog[g + rr*32][4*t + 3] = fmaf(sA, a0.w, sB * b0.w);
            if (t < 4)
                sog[g + rr*32][32 + t] = fmaf(sA, pA[96 + t], sB * pB[96 + t]);
        }
    }
    __syncthreads();
    for (int idx = tid; idx < 64 * 12; idx += 256) {
        const int ri = idx / 12, p = idx % 12;
        const int rowi = b * Ll + it * 64 + ri;
        const float ox = sog[ri][p*3 + 0] - trans[(size_t)rowi*3 + 0] * 0.1f;
        const float oy = sog[ri][p*3 + 1] - trans[(size_t)rowi*3 + 1] * 0.1f;
        const float oz = sog[ri][p*3 + 2] - trans[(size_t)rowi*3 + 2] * 0.1f;
        const float* R = rots + (size_t)rowi * 9;
        const float opx = fmaf(R[0], ox, fmaf(R[3], oy, R[6] * oz));
        const float opy = fmaf(R[1], ox, fmaf(R[4], oy, R[7] * oz));
        const float opz = fmaf(R[2], ox, fmaf(R[5], oy, R[8] * oz));
        const size_t base = (size_t)rowi * CATW + 512 + h*36 + p*3;
        cat[base + 0] = opx; cat[base + 1] = opy; cat[base + 2] = opz;
        cat[(size_t)rowi * CATW + 800 + h*12 + p] =
            sqrtf(opx*opx + opy*opy + opz*opz + 1e-8f);
    }
}

// ---------------------------------------------------------------------------
__global__ __launch_bounds__(384) void add_ln(
    const float* __restrict__ x, const float* __restrict__ y,
    const float* __restrict__ gw, const float* __restrict__ bw,
    float* __restrict__ out)
{
    __shared__ float red[6];
    const int row = blockIdx.x;
    const int c = threadIdx.x;
    const float v = x[(size_t)row*CSd + c] + y[(size_t)row*CSd + c];
    float s = v;
#pragma unroll
    for (int off = 32; off; off >>= 1) s += __shfl_down(s, off, 64);
    if ((c & 63) == 0) red[c >> 6] = s;
    __syncthreads();
    float mean = 0.f;
#pragma unroll
    for (int w = 0; w < 6; ++w) mean += red[w];
    mean *= (1.f / CSd);
    __syncthreads();
    const float d = v - mean;
    float sq = d * d;
#pragma unroll
    for (int off = 32; off; off >>= 1) sq += __shfl_down(sq, off, 64);
    if ((c & 63) == 0) red[c >> 6] = sq;
    __syncthreads();
    float var = 0.f;
#pragma unroll
    for (int w = 0; w < 6; ++w) var += red[w];
    var *= (1.f / CSd);
    out[(size_t)row*CSd + c] = d * rsqrtf(var + 1e-5f) * gw[c] + bw[c];
}

__global__ __launch_bounds__(64) void backbone(
    const float* __restrict__ s2, const float* __restrict__ Wbb,
    const float* __restrict__ bbb, const float* __restrict__ rots,
    const float* __restrict__ trans,
    float* __restrict__ outR, float* __restrict__ outT)
{
    const int row = blockIdx.x;
    const int t = threadIdx.x;
    float part[6] = {};
    for (int c = t; c < CSd; c += 64) {
        const float sv = s2[(size_t)row*CSd + c];
#pragma unroll
        for (int j = 0; j < 6; ++j) part[j] = fmaf(sv, Wbb[c*6 + j], part[j]);
    }
#pragma unroll
    for (int j = 0; j < 6; ++j) {
#pragma unroll
        for (int off = 32; off; off >>= 1) part[j] += __shfl_down(part[j], off, 64);
    }
    if (t == 0) {
        float u[6];
#pragma unroll
        for (int j = 0; j < 6; ++j) u[j] = part[j] + bbb[j];
        const float inv = 1.f / sqrtf(1.f + u[0]*u[0] + u[1]*u[1] + u[2]*u[2]);
        const float w = inv, x = u[0]*inv, y = u[1]*inv, z = u[2]*inv;
        const float Ru[9] = {
            1.f - 2.f*(y*y + z*z), 2.f*(x*y - w*z), 2.f*(x*z + w*y),
            2.f*(x*y + w*z), 1.f - 2.f*(x*x + z*z), 2.f*(y*z - w*x),
            2.f*(x*z - w*y), 2.f*(y*z + w*x), 1.f - 2.f*(x*x + y*y)};
        float R[9];
#pragma unroll
        for (int i2 = 0; i2 < 9; ++i2) R[i2] = rots[(size_t)row*9 + i2];
#pragma unroll
        for (int xi = 0; xi < 3; ++xi)
#pragma unroll
            for (int zi = 0; zi < 3; ++zi)
                outR[(size_t)row*9 + xi*3 + zi] =
                    fmaf(R[xi*3+0], Ru[0+zi],
                    fmaf(R[xi*3+1], Ru[3+zi], R[xi*3+2] * Ru[6+zi]));
#pragma unroll
        for (int xi = 0; xi < 3; ++xi)
            outT[(size_t)row*3 + xi] =
                fmaf(R[xi*3+0], u[3],
                fmaf(R[xi*3+1], u[4], R[xi*3+2] * u[5])) +
                trans[(size_t)row*3 + xi];
    }
}

// ---------------------------------------------------------------------------
extern "C" void kernel_launch(void* const* d_in, const int* in_sizes, int n_in,
                              void* d_out, int out_size, void* d_ws, size_t ws_size,
                              hipStream_t stream)
{
    const float* s      = (const float*)d_in[0];
    const float* trans  = (const float*)d_in[1];
    const float* rots   = (const float*)d_in[2];
    const float* mask   = (const float*)d_in[3];
    const float* We_s   = (const float*)d_in[4];
    const float* be_s   = (const float*)d_in[5];
    const float* We_mlp = (const float*)d_in[6];
    const float* be_mlp = (const float*)d_in[7];
    const float* Wf1    = (const float*)d_in[8];
    const float* bf1    = (const float*)d_in[9];
    const float* Wf2    = (const float*)d_in[10];
    const float* bf2    = (const float*)d_in[11];
    const float* Wq     = (const float*)d_in[12];
    const float* Wk     = (const float*)d_in[13];
    const float* Wv     = (const float*)d_in[14];
    const float* Wqp    = (const float*)d_in[15];
    const float* Wkp    = (const float*)d_in[16];
    const float* Wvp    = (const float*)d_in[17];
    const float* gamma  = (const float*)d_in[18];
    const float* Wb1    = (const float*)d_in[19];
    const float* Wb2    = (const float*)d_in[20];
    const float* Wz1    = (const float*)d_in[21];
    const float* Wz2    = (const float*)d_in[22];
    const float* Wout   = (const float*)d_in[23];
    const float* bout   = (const float*)d_in[24];
    const float* ln1_g  = (const float*)d_in[25];
    const float* ln1_b  = (const float*)d_in[26];
    const float* Wt1    = (const float*)d_in[27];
    const float* bt1    = (const float*)d_in[28];
    const float* Wt2    = (const float*)d_in[29];
    const float* bt2    = (const float*)d_in[30];
    const float* Wt3    = (const float*)d_in[31];
    const float* bt3    = (const float*)d_in[32];
    const float* ln2_g  = (const float*)d_in[33];
    const float* ln2_b  = (const float*)d_in[34];
    const float* Wbb    = (const float*)d_in[35];
    const float* bbb    = (const float*)d_in[36];

    float* ws = (float*)d_ws;
    size_t off = 0;
    auto alloc = [&](size_t n) { float* p = ws + off; off += n; return p; };
    float* cat2  = alloc((size_t)BL * CAT2W);
    float* hmid  = alloc((size_t)BL * 128);
    float* z12   = alloc((size_t)BL * 512);
    float* bfi   = alloc((size_t)BL * 16);
    float* bfj   = alloc((size_t)BL * 16);
    float* zv1   = alloc((size_t)BL * 64);
    float* zv2   = alloc((size_t)BL * 64);
    float* qkv   = alloc((size_t)BL * QKVW);
    float* q2    = alloc((size_t)BL * 8);
    float* k2    = alloc((size_t)BL * 8);
    float* cat   = alloc((size_t)BL * CATW);
    float* tmp1  = alloc((size_t)BL * CSd);
    float* s1    = alloc((size_t)BL * CSd);
    float* Wpk   = alloc((size_t)CSd * QKVW);
    float* Wf12  = alloc((size_t)128 * 512);
    float* bf12  = alloc(512);
    float* partb = alloc((size_t)32 * 2 * Ll * PARTW);   // 44 MB j-split partials
    // aliases (lifetimes: z12 dead after z_derive; qkv dead after flash)
    float* h1    = z12;
    float* h2b   = qkv;
    float* tmp2  = tmp1;

    float* outS = (float*)d_out;
    float* outR = outS + (size_t)BL * CSd;
    float* outT = outR + (size_t)BL * 9;

    pack_qkv<<<dim3(CSd), dim3(256), 0, stream>>>(Wq, Wk, Wv, Wqp, Wkp, Wvp, Wpk);
    pack_f12<<<dim3(128), dim3(256), 0, stream>>>(Wf1, Wf2, bf1, bf2, Wf12, bf12);

    // edge embedder
    gemm_mfma<false,true><<<dim3(2,64), dim3(256), 0, stream>>>(s, CSd, We_s, be_s, cat2, CAT2W, 128, CSd);
    edge_feat<<<dim3(BL), dim3(128), 0, stream>>>(trans, cat2);
    gemm_mfma<true,true><<<dim3(2,64), dim3(256), 0, stream>>>(cat2, CAT2W, We_mlp, be_mlp, hmid, 128, 128, CAT2W);
    gemm_mfma<false,true><<<dim3(8,64), dim3(256), 0, stream>>>(hmid, 128, Wf12, bf12, z12, 512, 512, 128);
    z_derive<<<dim3(BL), dim3(256), 0, stream>>>(z12, mask, Wb1, Wb2, Wz1, Wz2, bfi, bfj, zv1, zv2);

    // fused QKV + point projections (N=2208 -> 35 n-tiles with guard)
    gemm_mfma<false,false><<<dim3(35,64), dim3(256), 0, stream>>>(s, CSd, Wpk, nullptr, qkv, QKVW, QKVW, CSd);
    to_global_k<<<dim3(BL), dim3(256), 0, stream>>>(rots, trans, qkv, q2, k2);

    // fused IPA attention (4 rows/group, j-split x2) -> partials -> combine
    flash_ipa4<<<dim3(512), dim3(256), 0, stream>>>(
        qkv, q2, k2, bfi, bfj, zv2, mask, gamma, partb);
    combine_ipa<<<dim3(512), dim3(256), 0, stream>>>(partb, zv1, rots, trans, cat);

    // output projection + residual + LN1
    gemm_mfma<false,true><<<dim3(6,64), dim3(256), 0, stream>>>(cat, CATW, Wout, bout, tmp1, CSd, CSd, CATW);
    add_ln<<<dim3(BL), dim3(384), 0, stream>>>(s, tmp1, ln1_g, ln1_b, s1);

    // transition
    gemm_mfma<true,true><<<dim3(6,64), dim3(256), 0, stream>>>(s1, CSd, Wt1, bt1, h1, CSd, CSd, CSd);
    gemm_mfma<true,true><<<dim3(6,64), dim3(256), 0, stream>>>(h1, CSd, Wt2, bt2, h2b, CSd, CSd, CSd);
    gemm_mfma<false,true><<<dim3(6,64), dim3(256), 0, stream>>>(h2b, CSd, Wt3, bt3, tmp2, CSd, CSd, CSd);
    add_ln<<<dim3(BL), dim3(384), 0, stream>>>(s1, tmp2, ln2_g, ln2_b, outS);

    // backbone update
    backbone<<<dim3(BL), dim3(64), 0, stream>>>(outS, Wbb, bbb, rots, trans, outR, outT);
}